// Round 10
// baseline (922.671 us; speedup 1.0000x reference)
//
#include <hip/hip_runtime.h>
#include <hip/hip_bf16.h>

#define BB 64
#define CIN 256
#define CC 576
#define NGR 9
#define SPC 64
#define HW7 49
#define HW14 196
#define HW28 784

__device__ __constant__ int EDGE_SRC_C[24] = {1,3, 0,2,4, 1,5, 0,4,6, 1,3,5,7, 2,4,8, 3,7, 4,6,8, 5,7};
__device__ __constant__ int EDGE_OFF_C[9]  = {0,2,5,7,10,14,17,19,22};
__device__ __constant__ int EDGE_CNT_C[9]  = {2,3,2,3,4,3,2,3,2};

static __device__ __forceinline__ float bf2f(__hip_bfloat16 v){ return __bfloat162float(v); }
static __device__ __forceinline__ __hip_bfloat16 f2bf(float v){ return __float2bfloat16(v); }
static __device__ __forceinline__ float ldin(const void* p, size_t i, int isbf){
  return isbf ? bf2f(((const __hip_bfloat16*)p)[i]) : ((const float*)p)[i];
}

using bfrag = __attribute__((ext_vector_type(8))) short;
using f32x4 = __attribute__((ext_vector_type(4))) float;

// ---- dtype detector ------------------------------------------------------
__global__ void detect_kernel(const unsigned short* xs, int* flag) {
  if (threadIdx.x==0 && blockIdx.x==0) {
    int plaus = 0;
    for (int i=0;i<64;i++){
      unsigned short u = xs[2*i];
      int e = (u>>7)&0xFF;
      if (e>=100 && e<=140) plaus++;
    }
    *flag = (plaus >= 40) ? 1 : 0;
  }
}

// ---- x: [64,256,14,14] ext -> act0 NHWC bf16 [64][196][256] --------------
__global__ __launch_bounds__(256) void xcvt_kernel(
    const void* __restrict__ x, const int* __restrict__ flagp,
    __hip_bfloat16* __restrict__ act0) {
  const int b = blockIdx.x, icb = blockIdx.y, pxb = blockIdx.z, t = threadIdx.x;
  const int isbf = *flagp;
  __shared__ float lds[32][29];
  for (int idx=t; idx<32*28; idx+=256){
    int i = idx/28, j = idx - i*28;
    lds[i][j] = ldin(x, ((size_t)b*CIN + icb*32+i)*HW14 + pxb*28 + j, isbf);
  }
  __syncthreads();
  for (int idx=t; idx<28*32; idx+=256){
    int j = idx >> 5, i = idx & 31;
    act0[((size_t)b*HW14 + pxb*28 + j)*CIN + icb*32 + i] = f2bf(lds[i][j]);
  }
}

// ---- conv0 weights [576][256][9] ext -> [9][8][576][32] bf16 -------------
__global__ __launch_bounds__(256) void wcvt0_kernel(
    const void* __restrict__ w, const int* __restrict__ flagp,
    __hip_bfloat16* __restrict__ dst) {
  const int oc = blockIdx.x, t = threadIdx.x;
  const int isbf = *flagp;
  __shared__ float lds[2304];
  for (int idx=t; idx<2304; idx+=256)
    lds[idx] = ldin(w, (size_t)oc*2304 + idx, isbf);
  __syncthreads();
  for (int idx=t; idx<2304; idx+=256){
    int koff = idx >> 8, rem = idx & 255;
    int icb = rem >> 5, ici = rem & 31;
    dst[(((size_t)koff*8 + icb)*CC + oc)*32 + ici] = f2bf(lds[rem*9 + koff]);
  }
}

// ---- convs_w layer li [576][576][9] ext -> [9][18][576][32] bf16 ---------
// (fallback path when workspace too small for wall buffer)
__global__ __launch_bounds__(256) void wcvtL_kernel(
    const void* __restrict__ w, int li, const int* __restrict__ flagp,
    __hip_bfloat16* __restrict__ dst) {
  const int oc = blockIdx.x, t = threadIdx.x;
  const int isbf = *flagp;
  __shared__ float lds[5184];
  for (int idx=t; idx<5184; idx+=256)
    lds[idx] = ldin(w, ((size_t)li*CC + oc)*5184 + idx, isbf);
  __syncthreads();
  for (int idx=t; idx<5184; idx+=256){
    int koff = idx / 576, rem = idx - koff*576;
    int icb = rem >> 5, ici = rem & 31;
    dst[(((size_t)koff*18 + icb)*CC + oc)*32 + ici] = f2bf(lds[rem*9 + koff]);
  }
}

// ---- ALL 7 conv layers' weights, v2: vectorized + full-line writes -------
__global__ __launch_bounds__(256) void wcvtAll2_kernel(
    const void* __restrict__ w, const int* __restrict__ flagp,
    __hip_bfloat16* __restrict__ dst_base) {
  const int oc0 = blockIdx.x*2, li = blockIdx.y, t = threadIdx.x;
  const int isbf = *flagp;
  __hip_bfloat16* dst = dst_base + (size_t)li * (9u*18u*576u*32u);
  __shared__ alignas(16) __hip_bfloat16 lds[2*5184];

  if (isbf){
    const unsigned short* ws = (const unsigned short*)w;
    for (int idx=t; idx<1296; idx+=256){
      int ocl = idx/648, j = idx - ocl*648;
      *(bfrag*)(lds + ocl*5184 + j*8) =
        *(const bfrag*)(ws + ((size_t)(li*CC + oc0+ocl))*5184 + j*8);
    }
  } else {
    const float* wf = (const float*)w;
    for (int idx=t; idx<1296; idx+=256){
      int ocl = idx/648, j = idx - ocl*648;
      const float* s = wf + ((size_t)(li*CC + oc0+ocl))*5184 + j*8;
      f32x4 v0 = *(const f32x4*)(s);
      f32x4 v1 = *(const f32x4*)(s+4);
      alignas(16) __hip_bfloat16 tmp[8];
      #pragma unroll
      for (int u=0;u<4;u++){ tmp[u] = f2bf(v0[u]); tmp[4+u] = f2bf(v1[u]); }
      *(bfrag*)(lds + ocl*5184 + j*8) = *(const bfrag*)tmp;
    }
  }
  __syncthreads();

  for (int idx=t; idx<1296; idx+=256){
    int g = idx>>1, ocl = idx&1;
    int koff = g/72, r = g - koff*72;
    int icb = r>>2, q = r&3;
    const __hip_bfloat16* src = lds + ocl*5184;
    alignas(16) __hip_bfloat16 tmp[8];
    #pragma unroll
    for (int u=0;u<8;u++)
      tmp[u] = src[(icb*32 + q*8 + u)*9 + koff];
    *(bfrag*)(dst + (((size_t)koff*18 + icb)*CC + (oc0+ocl))*32 + q*8) =
        *(const bfrag*)tmp;
  }
}

// ---- epilogue for conv0 (64 ch / 4 GN groups, validated) -----------------
static __device__ __forceinline__ void epilogue_gn(
    float* s_out, float* s_stats, const f32x4 (&acc)[2][2],
    int wm, int wn, int ln, int quad, int t,
    const void* bias, int bias_off,
    const void* gamma, const void* beta, int goff,
    int nbb, int isbf, int b,
    __hip_bfloat16* __restrict__ out)
{
  __syncthreads();
  #pragma unroll
  for (int nf=0; nf<2; nf++){
    int chl = wn*32 + nf*16 + ln;
    float bv = ldin(bias, (size_t)bias_off + nbb + chl, isbf);
    #pragma unroll
    for (int mf=0; mf<2; mf++){
      #pragma unroll
      for (int r=0; r<4; r++){
        int px = wm*32 + mf*16 + quad*4 + r;
        s_out[chl*65 + px] = acc[mf][nf][r] + bv;
      }
    }
  }
  __syncthreads();
  {
    int wv = t >> 6, l = t & 63;
    float s=0.f, ss=0.f;
    for (int j=l; j<784; j+=64){
      int cq = j/49, px = j - cq*49;
      float v = s_out[(wv*16+cq)*65 + px];
      s += v; ss += v*v;
    }
    #pragma unroll
    for (int o=32;o>0;o>>=1){ s+=__shfl_down(s,o); ss+=__shfl_down(ss,o); }
    if (l==0){
      float mean=s/784.f, var=ss/784.f-mean*mean;
      s_stats[wv*2]=mean; s_stats[wv*2+1]=rsqrtf(fmaxf(var,0.f)+1e-5f);
    }
  }
  __syncthreads();
  for (int idx=t; idx<392; idx+=256){
    int px = idx>>3, ck = idx&7;
    alignas(16) __hip_bfloat16 tmp[8];
    #pragma unroll
    for (int u=0;u<8;u++){
      int chl = ck*8+u;
      int gi = chl>>4;
      float ga = ldin(gamma, (size_t)goff + nbb + chl, isbf);
      float be = ldin(beta,  (size_t)goff + nbb + chl, isbf);
      float v = (s_out[chl*65+px]-s_stats[gi*2])*s_stats[gi*2+1]*ga + be;
      tmp[u] = f2bf(fmaxf(v,0.f));
    }
    *(bfrag*)(out + ((size_t)b*64+px)*CC + nbb + ck*8) = *(const bfrag*)tmp;
  }
}

// ---- conv3x3 s1 p1 + GN + ReLU, v9: v8 + reg-burst weight loads ----------
// flat grid 1152, XCD swizzle sw=(id&7)*144+(id>>3). Wave tile 32Mx16N,
// K-chunk 64 (9 barriers), T14 A-staging. NEW vs v8: __launch_bounds__(256,4)
// raises the VGPR cap to 128 (grid gives only 4.5 blocks/CU, so 8-wave/SIMD
// occupancy is unattainable anyway; the default cap starved ILP at 48 VGPR),
// and all 18 weight frags of a chunk are burst-loaded into wreg[] BEFORE the
// MFMA loop -> 18 loads in flight (one L2 latency, not a serial chain).
__global__ __launch_bounds__(256, 4) void conv3_v9_kernel(
    const __hip_bfloat16* __restrict__ A,     // NHWC [64][64][576], px<49 valid
    const __hip_bfloat16* __restrict__ Wb,    // [9][18][576][32]
    const void* __restrict__ bias, int bias_off,
    const void* __restrict__ gamma, const void* __restrict__ beta, int goff,
    const int* __restrict__ flagp,
    __hip_bfloat16* __restrict__ out) {
  const int t = threadIdx.x;
  const int l = t & 63, w = t >> 6;
  const int wm = w & 1, wn = (w >> 1) & 1;
  const int ln = l & 15, quad = l >> 4;
  const int id = blockIdx.x;
  const int sw = (id & 7)*144 + (id >> 3);   // XCD-contiguous remap (bijective)
  const int b = sw & 63, nbb = (sw >> 6)*32;
  const int isbf = *flagp;

  __shared__ alignas(16) char smem[14400];
  __shared__ float s_stats[4];
  __hip_bfloat16* sA0 = (__hip_bfloat16*)smem;
  __hip_bfloat16* sA1 = (__hip_bfloat16*)(smem + 7200);
  float* s_out = (float*)smem;

  if (t < 16){
    bfrag z = {0,0,0,0,0,0,0,0};
    __hip_bfloat16* sb = (t<8)? sA0 : sA1;
    *(bfrag*)(sb + 49*72 + (t&7)*8) = z;
  }

  int r0a[9], r1a[9];
  {
    int p0 = wm*32 + ln, p1 = p0+16;
    int y0=p0/7, x0=p0-y0*7, y1=p1/7, x1=p1-y1*7;
    bool v0=p0<49, v1=p1<49;
    #pragma unroll
    for (int koff=0;koff<9;koff++){
      int dy=koff/3-1, dx=koff-(koff/3)*3-1;
      int sy0=y0+dy,sx0=x0+dx, sy1=y1+dy,sx1=x1+dx;
      r0a[koff] = (v0&&sy0>=0&&sy0<7&&sx0>=0&&sx0<7)? sy0*7+sx0 : 49;
      r1a[koff] = (v1&&sy1>=0&&sy1<7&&sx1>=0&&sx1<7)? sy1*7+sx1 : 49;
    }
  }

  f32x4 acc2[2];
  acc2[0] = (f32x4){0.f,0.f,0.f,0.f};
  acc2[1] = (f32x4){0.f,0.f,0.f,0.f};

  const int i0r = t>>3, is8 = (t&7)*8;
  const int i1r = i0r + 32;
  const bool has1 = (t < 136);
  const __hip_bfloat16* Ab = A + (size_t)b*64*CC;

  *(bfrag*)(sA0 + i0r*72 + is8) = *(const bfrag*)(Ab + (size_t)i0r*CC + is8);
  if (has1)
    *(bfrag*)(sA0 + i1r*72 + is8) = *(const bfrag*)(Ab + (size_t)i1r*CC + is8);
  __syncthreads();

  const int nidx = nbb + wn*16 + ln;
  const __hip_bfloat16* wbase = Wb + (size_t)nidx*32 + quad*8;
  for (int c=0; c<9; c++){
    __hip_bfloat16* curb = (c&1)? sA1 : sA0;

    // burst-load all 18 weight frags of this chunk (72 VGPR, all in flight)
    bfrag wreg[18];
    #pragma unroll
    for (int koff=0;koff<9;koff++)
      #pragma unroll
      for (int ks=0; ks<2; ks++)
        wreg[koff*2+ks] =
            *(const bfrag*)(wbase + (size_t)(koff*18 + c*2 + ks)*18432);

    bfrag rs0, rs1;
    const bool pf = (c<8);
    if (pf){
      rs0 = *(const bfrag*)(Ab + (size_t)i0r*CC + (c+1)*64 + is8);
      if (has1) rs1 = *(const bfrag*)(Ab + (size_t)i1r*CC + (c+1)*64 + is8);
    }

    #pragma unroll
    for (int koff=0;koff<9;koff++){
      const int ra0 = r0a[koff]*72 + quad*8;
      const int ra1 = r1a[koff]*72 + quad*8;
      #pragma unroll
      for (int ks=0; ks<2; ks++){
        bfrag a0 = *(const bfrag*)(curb + ra0 + ks*32);
        bfrag a1 = *(const bfrag*)(curb + ra1 + ks*32);
        acc2[0] = __builtin_amdgcn_mfma_f32_16x16x32_bf16(a0, wreg[koff*2+ks], acc2[0], 0,0,0);
        acc2[1] = __builtin_amdgcn_mfma_f32_16x16x32_bf16(a1, wreg[koff*2+ks], acc2[1], 0,0,0);
      }
    }
    if (pf){
      __hip_bfloat16* nxtb = (c&1)? sA0 : sA1;
      *(bfrag*)(nxtb + i0r*72 + is8) = rs0;
      if (has1) *(bfrag*)(nxtb + i1r*72 + is8) = rs1;
    }
    __syncthreads();
  }

  // epilogue: 32 ch x 49 px, 2 GN groups of 16 ch
  {
    const int chl = wn*16 + ln;
    float bv = ldin(bias, (size_t)bias_off + nbb + chl, isbf);
    #pragma unroll
    for (int mf=0; mf<2; mf++)
      #pragma unroll
      for (int r=0;r<4;r++){
        int px = wm*32 + mf*16 + quad*4 + r;
        s_out[chl*65 + px] = acc2[mf][r] + bv;
      }
  }
  __syncthreads();
  {
    int wv = t >> 6, l2 = t & 63;
    if (wv < 2){
      float s=0.f, ss=0.f;
      for (int j=l2; j<784; j+=64){
        int cq = j/49, px = j - cq*49;
        float v = s_out[(wv*16+cq)*65 + px];
        s += v; ss += v*v;
      }
      #pragma unroll
      for (int o=32;o>0;o>>=1){ s+=__shfl_down(s,o); ss+=__shfl_down(ss,o); }
      if (l2==0){
        float mean=s/784.f, var=ss/784.f-mean*mean;
        s_stats[wv*2]=mean; s_stats[wv*2+1]=rsqrtf(fmaxf(var,0.f)+1e-5f);
      }
    }
  }
  __syncthreads();
  if (t < 196){
    int px = t>>2, ck = t&3;
    alignas(16) __hip_bfloat16 tmp[8];
    #pragma unroll
    for (int u=0;u<8;u++){
      int chl = ck*8+u;
      int gi = chl>>4;
      float ga = ldin(gamma, (size_t)goff + nbb + chl, isbf);
      float be = ldin(beta,  (size_t)goff + nbb + chl, isbf);
      float v = (s_out[chl*65+px]-s_stats[gi*2])*s_stats[gi*2+1]*ga + be;
      tmp[u] = f2bf(fmaxf(v,0.f));
    }
    *(bfrag*)(out + ((size_t)b*64+px)*CC + nbb + ck*8) = *(const bfrag*)tmp;
  }
}

// ---- conv0 3x3 s2 p1 + GN + ReLU, chunked LDS A, MFMA (validated) --------
__global__ __launch_bounds__(256) void conv0_fused_kernel(
    const __hip_bfloat16* __restrict__ A,     // NHWC [64][196][256]
    const __hip_bfloat16* __restrict__ Wb,    // [9][8][576][32]
    const void* __restrict__ bias,
    const void* __restrict__ gamma, const void* __restrict__ beta,
    const int* __restrict__ flagp,
    __hip_bfloat16* __restrict__ out) {       // NHWC [64][64][576]
  const int t = threadIdx.x;
  const int l = t & 63, w = t >> 6;
  const int wm = w & 1, wn = w >> 1;
  const int ln = l & 15, quad = l >> 4;
  const int b = blockIdx.x, nbb = blockIdx.y*64;

  __shared__ alignas(16) __hip_bfloat16 sC[197*40];
  __shared__ alignas(16) float s_out_arr[64*65];
  __shared__ float s_stats[8];

  if (t < 4){
    bfrag z = {0,0,0,0,0,0,0,0};
    *(bfrag*)(sC + 196*40 + t*8) = z;
  }

  int yy[2], xx[2]; bool pv[2];
  #pragma unroll
  for (int mf=0; mf<2; mf++){
    int p = wm*32 + mf*16 + ln;
    pv[mf] = p<49; yy[mf]=p/7; xx[mf]=p-yy[mf]*7;
  }

  f32x4 acc[2][2];
  #pragma unroll
  for (int i=0;i<2;i++)
    #pragma unroll
    for (int j=0;j<2;j++) acc[i][j] = (f32x4){0.f,0.f,0.f,0.f};

  for (int icb=0; icb<8; icb++){
    __syncthreads();
    for (int idx=t*8; idx<6272; idx+=2048){
      int px = idx>>5, ic = idx&31;
      *(bfrag*)(sC + px*40 + ic) = *(const bfrag*)(A + ((size_t)b*196+px)*256 + icb*32 + ic);
    }
    __syncthreads();
    for (int koff=0; koff<9; koff++){
      const int dy = koff/3 - 1, dx = koff - (koff/3)*3 - 1;
      int sy0=2*yy[0]+dy, sx0=2*xx[0]+dx;
      int r0 = (pv[0]&&sy0>=0&&sy0<14&&sx0>=0&&sx0<14) ? sy0*14+sx0 : 196;
      int sy1=2*yy[1]+dy, sx1=2*xx[1]+dx;
      int r1 = (pv[1]&&sy1>=0&&sy1<14&&sx1>=0&&sx1<14) ? sy1*14+sx1 : 196;
      bfrag a0 = *(const bfrag*)(sC + r0*40 + quad*8);
      bfrag a1 = *(const bfrag*)(sC + r1*40 + quad*8);
      const __hip_bfloat16* wp = Wb + ((size_t)(koff*8+icb)*576 + nbb + wn*32 + ln)*32 + quad*8;
      bfrag b0 = *(const bfrag*)(wp);
      bfrag b1 = *(const bfrag*)(wp + 16*32);
      acc[0][0] = __builtin_amdgcn_mfma_f32_16x16x32_bf16(a0, b0, acc[0][0], 0,0,0);
      acc[1][0] = __builtin_amdgcn_mfma_f32_16x16x32_bf16(a1, b0, acc[1][0], 0,0,0);
      acc[0][1] = __builtin_amdgcn_mfma_f32_16x16x32_bf16(a0, b1, acc[0][1], 0,0,0);
      acc[1][1] = __builtin_amdgcn_mfma_f32_16x16x32_bf16(a1, b1, acc[1][1], 0,0,0);
    }
  }

  epilogue_gn(s_out_arr, s_stats, acc, wm, wn, ln, quad, t,
              bias, 0, gamma, beta, 0, nbb, *flagp, b, out);
}

// ---- depthwise 5x5 per edge: F NHWC -> Y[e][(b*49+px)][64] bf16 ----------
__global__ __launch_bounds__(256) void dw_edge_kernel(
    const __hip_bfloat16* __restrict__ F,
    const void* __restrict__ dw_w,   // [24][64][25]
    const void* __restrict__ dw_b,   // [24][64]
    const int* __restrict__ flagp,
    __hip_bfloat16* __restrict__ Y) {
  const int b = blockIdx.x, e = blockIdx.y, t = threadIdx.x;
  const int isbf = *flagp;
  const int src = EDGE_SRC_C[e];
  __shared__ alignas(16) __hip_bfloat16 sA[50*72];   // 49 px rows + zero row
  for (int idx=t; idx<400; idx+=256){
    if (idx < 392){
      int px = idx>>3, ic = (idx&7)*8;
      *(bfrag*)(sA + px*72 + ic) = *(const bfrag*)(F + ((size_t)b*64+px)*CC + src*64 + ic);
    } else {
      bfrag z = {0,0,0,0,0,0,0,0};
      *(bfrag*)(sA + 49*72 + (idx-392)*8) = z;
    }
  }
  __syncthreads();
  const int ch = t & 63, wv = t >> 6;
  float wd[25];
  #pragma unroll
  for (int j=0;j<25;j++) wd[j] = ldin(dw_w, (size_t)e*1600 + ch*25 + j, isbf);
  float dwb = ldin(dw_b, e*64 + ch, isbf);
  for (int px=wv; px<49; px+=4){
    int oy=px/7, ox=px-oy*7;
    float a = dwb;
    #pragma unroll
    for (int u=0;u<5;u++){
      int py = oy+u-2;
      bool vy = (py>=0)&&(py<7);
      #pragma unroll
      for (int v=0;v<5;v++){
        int pxx = ox+v-2;
        int r = (vy && pxx>=0 && pxx<7) ? py*7+pxx : 49;
        a += bf2f(sA[r*72 + ch]) * wd[u*5+v];
      }
    }
    Y[((size_t)(e*64+b)*49 + px)*64 + ch] = f2bf(a);
  }
}

// ---- pack pointwise weights to bf16 [24][64oc][64ic] ---------------------
__global__ __launch_bounds__(256) void pwpack_kernel(
    const void* __restrict__ pw_fo, const void* __restrict__ pw_so,
    const int* __restrict__ flagp,
    __hip_bfloat16* __restrict__ dfo, __hip_bfloat16* __restrict__ dso) {
  const int e = blockIdx.x, t = threadIdx.x;
  const int isbf = *flagp;
  for (int idx=t; idx<4096; idx+=256){
    dfo[(size_t)e*4096+idx] = f2bf(ldin(pw_fo, (size_t)e*4096+idx, isbf));
    dso[(size_t)e*4096+idx] = f2bf(ldin(pw_so, (size_t)e*4096+idx, isbf));
  }
}

// ---- pointwise + segment-sum via MFMA: out = base + sum_e Y_e @ pw_e^T ---
__global__ __launch_bounds__(256) void pw_seg_kernel(
    const __hip_bfloat16* __restrict__ Y,     // [24][3136][64]
    const __hip_bfloat16* __restrict__ base,  // NHWC [64][64][576]
    const __hip_bfloat16* __restrict__ pwb,   // [24][64oc][64ic] bf16
    const void* __restrict__ pw_b,            // [24][64] ext
    const int* __restrict__ flagp,
    __hip_bfloat16* __restrict__ out) {       // NHWC
  const int t = threadIdx.x, l = t & 63, w = t >> 6;
  const int wm = w & 1, wn = w >> 1;
  const int ln = l & 15, quad = l >> 4;
  const int dst = blockIdx.y;
  const int mt = blockIdx.x*64 + wm*32;
  const int m0 = mt + ln, m1 = m0 + 16;

  f32x4 acc[2][2];
  #pragma unroll
  for (int i=0;i<2;i++)
    #pragma unroll
    for (int j=0;j<2;j++) acc[i][j] = (f32x4){0.f,0.f,0.f,0.f};

  const int eoff = EDGE_OFF_C[dst], ecnt = EDGE_CNT_C[dst];
  for (int k=0;k<ecnt;k++){
    const __hip_bfloat16* Ye = Y + (size_t)(eoff+k)*3136*64;
    const __hip_bfloat16* pe = pwb + (size_t)(eoff+k)*4096;
    #pragma unroll
    for (int ks=0; ks<2; ks++){
      const int kq = ks*32 + quad*8;
      bfrag a0 = *(const bfrag*)(Ye + (size_t)m0*64 + kq);
      bfrag a1 = *(const bfrag*)(Ye + (size_t)m1*64 + kq);
      bfrag b0 = *(const bfrag*)(pe + (wn*32+ln)*64 + kq);
      bfrag b1 = *(const bfrag*)(pe + (wn*32+ln+16)*64 + kq);
      acc[0][0] = __builtin_amdgcn_mfma_f32_16x16x32_bf16(a0, b0, acc[0][0], 0,0,0);
      acc[1][0] = __builtin_amdgcn_mfma_f32_16x16x32_bf16(a1, b0, acc[1][0], 0,0,0);
      acc[0][1] = __builtin_amdgcn_mfma_f32_16x16x32_bf16(a0, b1, acc[0][1], 0,0,0);
      acc[1][1] = __builtin_amdgcn_mfma_f32_16x16x32_bf16(a1, b1, acc[1][1], 0,0,0);
    }
  }

  const int isbf = *flagp;
  #pragma unroll
  for (int nf=0; nf<2; nf++){
    int n = wn*32 + nf*16 + ln;
    float pbs = 0.f;
    for (int k=0;k<ecnt;k++) pbs += ldin(pw_b, (size_t)(eoff+k)*64 + n, isbf);
    #pragma unroll
    for (int mf=0; mf<2; mf++){
      #pragma unroll
      for (int r=0; r<4; r++){
        int m = mt + mf*16 + quad*4 + r;
        int bb = m/49, px = m - bb*49;
        size_t oi = ((size_t)bb*64 + px)*CC + dst*64 + n;
        out[oi] = f2bf(bf2f(base[oi]) + acc[mf][nf][r] + pbs);
      }
    }
  }
}

// ---- up1_w [576][64][16] ext -> wpack [9][16tap][64oc][64ic] bf16 --------
__global__ __launch_bounds__(256) void wpack_dc1_kernel(
    const void* __restrict__ w1, const int* __restrict__ flagp,
    __hip_bfloat16* __restrict__ dst) {
  const int gtap = blockIdx.x, t = threadIdx.x;
  const int isbf = *flagp;
  const int g = gtap >> 4, tap = gtap & 15;
  for (int idx=t; idx<64*64; idx+=256){
    int oc = idx >> 6, ic = idx & 63;
    dst[((size_t)gtap*64 + oc)*64 + ic] =
        f2bf(ldin(w1, ((size_t)(g*64+ic)*64 + oc)*16 + tap, isbf));
  }
}

// ---- deconv1 via parity-class MFMA: H NHWC -> mid NHWC [64][196][576] ----
// ConvTranspose2d(k=4,s=2,p=1): output pixel (oy,ox) uses exactly 2x2 taps
// with ky parity == (oy+1)&1, kx parity == (ox+1)&1. Grid (49 Mtiles, 4
// classes, 9 groups); M = 64b*49px per class tiles exactly into 49x64.
// NOTE: 64 consecutive m = b*49+p rows span up to THREE batches; three
// batch slices staged (slice 2 zero-filled when b0+2 > 63). Pad-72 stride.
__global__ __launch_bounds__(256) void dc1_cls_kernel(
    const __hip_bfloat16* __restrict__ H,    // NHWC [64][64(px pad)][576]
    const __hip_bfloat16* __restrict__ Wp,   // [(g*16+tap)][oc][ic]
    const void* __restrict__ b1,
    const int* __restrict__ flagp,
    __hip_bfloat16* __restrict__ mid) {
  const int t = threadIdx.x;
  const int l = t & 63, w = t >> 6;
  const int wm = w & 1, wn = w >> 1;
  const int ln = l & 15, quad = l >> 4;
  const int Mt = blockIdx.x;        // 0..48, 64 rows of (b*49+p)
  const int cls = blockIdx.y;       // ry*2+rx
  const int g = blockIdx.z;
  const int ry = cls >> 1, rx = cls & 1;
  const int b0 = (Mt*64)/49;        // block spans b0 .. b0+2 (guarded)

  __shared__ alignas(16) __hip_bfloat16 sX[3*50*72];  // [bloc][px(+zero)][ic]

  {
    const bfrag z = {0,0,0,0,0,0,0,0};
    for (int idx=t; idx<1200; idx+=256){
      int bi = idx/400, rem = idx - bi*400;
      int p = rem>>3, ch = (rem&7)*8;
      bfrag v = z;
      if (p < 49 && (b0+bi) < 64)
        v = *(const bfrag*)(H + ((size_t)((b0+bi)*64) + p)*CC + g*64 + ch);
      *(bfrag*)(sX + (bi*50+p)*72 + ch) = v;
    }
  }

  // per-lane A row offsets for the 4 taps of this class
  int aoff[2][4];
  #pragma unroll
  for (int mf=0; mf<2; mf++){
    int m = Mt*64 + wm*32 + mf*16 + ln;
    int b = m/49, p = m - b*49;
    int py = p/7, pxx = p - py*7;
    int bloc = b - b0;
    #pragma unroll
    for (int kyi=0;kyi<2;kyi++){
      int iy = py + ry - kyi;
      bool vy = (iy>=0)&&(iy<7);
      #pragma unroll
      for (int kxi=0;kxi<2;kxi++){
        int ix = pxx + rx - kxi;
        int r = (vy && ix>=0 && ix<7) ? iy*7+ix : 49;
        aoff[mf][kyi*2+kxi] = (bloc*50 + r)*72 + quad*8;
      }
    }
  }

  f32x4 acc[2][2];
  #pragma unroll
  for (int i=0;i<2;i++)
    #pragma unroll
    for (int j=0;j<2;j++) acc[i][j] = (f32x4){0.f,0.f,0.f,0.f};

  __syncthreads();

  const int ky0 = 1-ry, kx0 = 1-rx;
  #pragma unroll
  for (int kyi=0;kyi<2;kyi++){
    #pragma unroll
    for (int kxi=0;kxi<2;kxi++){
      const int tap = (ky0+2*kyi)*4 + (kx0+2*kxi);
      const __hip_bfloat16* wb =
          Wp + ((size_t)(g*16+tap)*64 + wn*32 + ln)*64 + quad*8;
      const int ao0 = aoff[0][kyi*2+kxi], ao1 = aoff[1][kyi*2+kxi];
      #pragma unroll
      for (int half=0; half<2; half++){
        bfrag a0 = *(const bfrag*)(sX + ao0 + half*32);
        bfrag a1 = *(const bfrag*)(sX + ao1 + half*32);
        bfrag w0 = *(const bfrag*)(wb + half*32);
        bfrag w1 = *(const bfrag*)(wb + 16*64 + half*32);
        acc[0][0] = __builtin_amdgcn_mfma_f32_16x16x32_bf16(a0, w0, acc[0][0], 0,0,0);
        acc[1][0] = __builtin_amdgcn_mfma_f32_16x16x32_bf16(a1, w0, acc[1][0], 0,0,0);
        acc[0][1] = __builtin_amdgcn_mfma_f32_16x16x32_bf16(a0, w1, acc[0][1], 0,0,0);
        acc[1][1] = __builtin_amdgcn_mfma_f32_16x16x32_bf16(a1, w1, acc[1][1], 0,0,0);
      }
    }
  }

  const int isbf = *flagp;
  size_t ob[2][4];
  #pragma unroll
  for (int mf=0;mf<2;mf++){
    #pragma unroll
    for (int r=0;r<4;r++){
      int m = Mt*64 + wm*32 + mf*16 + quad*4 + r;
      int b = m/49, p = m - b*49;
      int py = p/7, pxx = p - py*7;
      int oy = 2*py + ry, ox = 2*pxx + rx;
      ob[mf][r] = ((size_t)b*196 + oy*14 + ox)*CC + g*64;
    }
  }
  #pragma unroll
  for (int nf=0;nf<2;nf++){
    int n = wn*32 + nf*16 + ln;
    float bv = ldin(b1, g*64 + n, isbf);
    #pragma unroll
    for (int mf=0;mf<2;mf++){
      #pragma unroll
      for (int r=0;r<4;r++)
        mid[ob[mf][r] + n] = f2bf(acc[mf][nf][r] + bv);
    }
  }
}

// ---- fused GN(9)+ReLU+deconv2: mid NHWC -> out 28x28, split in 2 halves --
// grid (b, g, z): z=0 -> out rows 0..13 (in rows 0..7), z=1 -> 14..27 (6..13)
__global__ __launch_bounds__(256) void dc2gn_kernel(
    const __hip_bfloat16* __restrict__ mid,   // [64][196][576] (bias only)
    const void* __restrict__ gamma, const void* __restrict__ beta,
    const void* __restrict__ w2,
    const void* __restrict__ b2,
    const int* __restrict__ flagp,
    void* __restrict__ outp,
    size_t out_elem_off) {
  const int isbf = *flagp;
  const int b=blockIdx.x, g=blockIdx.y, z=blockIdx.z, t=threadIdx.x;
  const int c = t & 63;
  __shared__ __hip_bfloat16 s_mid[64*113];   // [c][8 rows x 14 cols + pad]
  __shared__ float s_w2[64][17];
  __shared__ float red[8]; __shared__ float stats[2];
  const __hip_bfloat16* mbase = mid + (size_t)b*196*CC + g*64;

  {
    float s=0.f, ss=0.f;
    for (int idx=t; idx<12544; idx+=256){
      int ipx = idx>>6;
      float v = bf2f(mbase[(size_t)ipx*CC + (idx&63)]);
      s+=v; ss+=v*v;
    }
    #pragma unroll
    for (int o=32;o>0;o>>=1){ s+=__shfl_down(s,o); ss+=__shfl_down(ss,o); }
    int wid=t>>6;
    if ((t&63)==0){ red[wid]=s; red[4+wid]=ss; }
  }
  for (int idx=t; idx<1024; idx+=256)
    s_w2[idx>>4][idx&15] = ldin(w2, (g*SPC + (idx>>4))*16 + (idx&15), isbf);
  __syncthreads();
  if (t==0){
    float S=red[0]+red[1]+red[2]+red[3];
    float SS=red[4]+red[5]+red[6]+red[7];
    float mean=S/12544.f, var=SS/12544.f-mean*mean;
    stats[0]=mean; stats[1]=rsqrtf(fmaxf(var,0.f)+1e-5f);
  }
  __syncthreads();
  const float mean=stats[0], inv=stats[1];
  const int rbase = z*6;                 // input rows rbase..rbase+7
  {
    float ga = ldin(gamma, g*SPC+c, isbf), be = ldin(beta, g*SPC+c, isbf);
    for (int idx=t; idx<7168; idx+=256){
      int pl = idx>>6;                   // c = idx&63 == t&63 (stride 256)
      int ipx = (rbase + pl/14)*14 + (pl%14);
      float v = (bf2f(mbase[(size_t)ipx*CC + c])-mean)*inv*ga + be;
      s_mid[c*113 + pl] = f2bf(fmaxf(v, 0.f));
    }
  }
  __syncthreads();
  float b2v = ldin(b2, g, isbf);
  for (int p=t; p<392; p+=256){
    int oyl = p/28, ox = p - oyl*28;
    int oy = z*14 + oyl;
    float a = b2v;
    for (int cc=0; cc<64; cc++){
      #pragma unroll
      for (int kyi=0;kyi<2;kyi++){
        int ky=((oy+1)&1)+2*kyi; int ny=oy+1-ky;
        if (ny>=0){
          int iy=ny>>1;
          if (iy<14){
            int li = iy - rbase;     // in [0,8) by construction
            #pragma unroll
            for (int kxi=0;kxi<2;kxi++){
              int kx=((ox+1)&1)+2*kxi; int nx=ox+1-kx;
              if (nx>=0){
                int ix=nx>>1;
                if (ix<14) a += bf2f(s_mid[cc*113 + li*14 + ix])*s_w2[cc][ky*4+kx];
              }
            }
          }
        }
      }
    }
    size_t oidx = out_elem_off + ((size_t)b*NGR+g)*HW28 + oy*28 + ox;
    if (isbf) ((__hip_bfloat16*)outp)[oidx] = f2bf(a);
    else      ((float*)outp)[oidx] = a;
  }
}

extern "C" void kernel_launch(void* const* d_in, const int* in_sizes, int n_in,
                              void* d_out, int out_size, void* d_ws, size_t ws_size,
                              hipStream_t stream) {
  const void* x        = d_in[0];
  const void* convs_w0 = d_in[1];
  const void* convs_b0 = d_in[2];
  const void* convs_w  = d_in[3];
  const void* convs_b  = d_in[4];
  const void* gn_gamma = d_in[5];
  const void* gn_beta  = d_in[6];
  const void* fo_dw_w  = d_in[7];
  const void* fo_dw_b  = d_in[8];
  const void* fo_pw_w  = d_in[9];
  const void* fo_pw_b  = d_in[10];
  const void* so_dw_w  = d_in[11];
  const void* so_dw_b  = d_in[12];
  const void* so_pw_w  = d_in[13];
  const void* so_pw_b  = d_in[14];
  const void* up1_w    = d_in[15];
  const void* up1_b    = d_in[16];
  const void* sbn_g    = d_in[17];
  const void* sbn_b    = d_in[18];
  const void* up2_w    = d_in[19];
  const void* up2_b    = d_in[20];
  (void)in_sizes; (void)n_in; (void)out_size;

  int* flag = (int*)d_ws;
  char* wsb = (char*)d_ws + 16;
  __hip_bfloat16* act0   = (__hip_bfloat16*)(wsb);
  __hip_bfloat16* wbuf   = (__hip_bfloat16*)(wsb + 6422528);
  __hip_bfloat16* actA   = (__hip_bfloat16*)(wsb + 12394496);
  __hip_bfloat16* actB   = (__hip_bfloat16*)(wsb + 17113088);
  __hip_bfloat16* bufF   = (__hip_bfloat16*)(wsb + 21831680);
  __hip_bfloat16* secN   = (__hip_bfloat16*)(wsb + 26550272);
  __hip_bfloat16* wpack  = (__hip_bfloat16*)(wsb + 31268864);
  __hip_bfloat16* pwbF   = (__hip_bfloat16*)(wsb + 32448512);
  __hip_bfloat16* pwbS   = (__hip_bfloat16*)(wsb + 32645120);
  __hip_bfloat16* Y      = (__hip_bfloat16*)(wsb);
  __hip_bfloat16* mid    = (__hip_bfloat16*)(wsb);

  // merged weight-conversion buffer (7 layers), beyond all live buffers
  const size_t WL_ELEMS = (size_t)9*18*576*32;        // elems per layer
  const size_t wall_off = 33u*1024u*1024u;            // byte offset into wsb
  const bool bigws = ws_size >= 16 + wall_off + 7*WL_ELEMS*sizeof(__hip_bfloat16);
  __hip_bfloat16* wall = (__hip_bfloat16*)(wsb + wall_off);

  detect_kernel<<<1, 1, 0, stream>>>((const unsigned short*)x, flag);

  if (bigws)
    wcvtAll2_kernel<<<dim3(288,7), 256, 0, stream>>>(convs_w, flag, wall);

  xcvt_kernel<<<dim3(BB,8,7), 256, 0, stream>>>(x, flag, act0);
  wcvt0_kernel<<<CC, 256, 0, stream>>>(convs_w0, flag, wbuf);
  conv0_fused_kernel<<<dim3(64,9), 256, 0, stream>>>(
      act0, wbuf, convs_b0, gn_gamma, gn_beta, flag, actA);

  __hip_bfloat16* cur = actA; __hip_bfloat16* nxt = actB;
  for (int i=0;i<7;i++){
    const __hip_bfloat16* wb_i;
    if (bigws){
      wb_i = wall + (size_t)i*WL_ELEMS;
    } else {
      wcvtL_kernel<<<CC, 256, 0, stream>>>(convs_w, i, flag, wbuf);
      wb_i = wbuf;
    }
    conv3_v9_kernel<<<1152, 256, 0, stream>>>(
        cur, wb_i, convs_b, i*CC, gn_gamma, gn_beta, (i+1)*CC, flag, nxt);
    __hip_bfloat16* tmp=cur; cur=nxt; nxt=tmp;
  }
  // cur == actB (h, NHWC)

  wpack_dc1_kernel<<<144, 256, 0, stream>>>(up1_w, flag, wpack);
  pwpack_kernel<<<24, 256, 0, stream>>>(fo_pw_w, so_pw_w, flag, pwbF, pwbS);

  // edge pass 1: first = h + seg(pw(dw(h)))
  dw_edge_kernel<<<dim3(BB,24), 256, 0, stream>>>(cur, fo_dw_w, fo_dw_b, flag, Y);
  pw_seg_kernel<<<dim3(49,NGR), 256, 0, stream>>>(Y, cur, pwbF, fo_pw_b, flag, bufF);
  // edge pass 2: second = h + seg(pw(dw(first)))
  dw_edge_kernel<<<dim3(BB,24), 256, 0, stream>>>(bufF, so_dw_w, so_dw_b, flag, Y);
  pw_seg_kernel<<<dim3(49,NGR), 256, 0, stream>>>(Y, cur, pwbS, so_pw_b, flag, secN);

  // head 1 (input h = cur, NHWC)
  dc1_cls_kernel<<<dim3(49,4,NGR), 256, 0, stream>>>(cur, wpack, up1_b, flag, mid);
  dc2gn_kernel<<<dim3(BB,NGR,2), 256, 0, stream>>>(mid, sbn_g, sbn_b, up2_w, up2_b, flag, d_out, 0);
  // head 2 (input secN, NHWC)
  dc1_cls_kernel<<<dim3(49,4,NGR), 256, 0, stream>>>(secN, wpack, up1_b, flag, mid);
  dc2gn_kernel<<<dim3(BB,NGR,2), 256, 0, stream>>>(mid, sbn_g, sbn_b, up2_w, up2_b, flag, d_out, (size_t)BB*NGR*HW28);
}

// Round 12
// 888.767 us; speedup vs baseline: 1.0381x; 1.0381x over previous
//
#include <hip/hip_runtime.h>
#include <hip/hip_bf16.h>

#define BB 64
#define CIN 256
#define CC 576
#define NGR 9
#define SPC 64
#define HW7 49
#define HW14 196
#define HW28 784

__device__ __constant__ int EDGE_SRC_C[24] = {1,3, 0,2,4, 1,5, 0,4,6, 1,3,5,7, 2,4,8, 3,7, 4,6,8, 5,7};
__device__ __constant__ int EDGE_OFF_C[9]  = {0,2,5,7,10,14,17,19,22};
__device__ __constant__ int EDGE_CNT_C[9]  = {2,3,2,3,4,3,2,3,2};

static __device__ __forceinline__ float bf2f(__hip_bfloat16 v){ return __bfloat162float(v); }
static __device__ __forceinline__ __hip_bfloat16 f2bf(float v){ return __float2bfloat16(v); }
static __device__ __forceinline__ float ldin(const void* p, size_t i, int isbf){
  return isbf ? bf2f(((const __hip_bfloat16*)p)[i]) : ((const float*)p)[i];
}

using bfrag = __attribute__((ext_vector_type(8))) short;
using f32x4 = __attribute__((ext_vector_type(4))) float;

// ---- dtype detector ------------------------------------------------------
__global__ void detect_kernel(const unsigned short* xs, int* flag) {
  if (threadIdx.x==0 && blockIdx.x==0) {
    int plaus = 0;
    for (int i=0;i<64;i++){
      unsigned short u = xs[2*i];
      int e = (u>>7)&0xFF;
      if (e>=100 && e<=140) plaus++;
    }
    *flag = (plaus >= 40) ? 1 : 0;
  }
}

// ---- x: [64,256,14,14] ext -> act0 NHWC bf16 [64][196][256] --------------
__global__ __launch_bounds__(256) void xcvt_kernel(
    const void* __restrict__ x, const int* __restrict__ flagp,
    __hip_bfloat16* __restrict__ act0) {
  const int b = blockIdx.x, icb = blockIdx.y, pxb = blockIdx.z, t = threadIdx.x;
  const int isbf = *flagp;
  __shared__ float lds[32][29];
  for (int idx=t; idx<32*28; idx+=256){
    int i = idx/28, j = idx - i*28;
    lds[i][j] = ldin(x, ((size_t)b*CIN + icb*32+i)*HW14 + pxb*28 + j, isbf);
  }
  __syncthreads();
  for (int idx=t; idx<28*32; idx+=256){
    int j = idx >> 5, i = idx & 31;
    act0[((size_t)b*HW14 + pxb*28 + j)*CIN + icb*32 + i] = f2bf(lds[i][j]);
  }
}

// ---- conv0 weights [576][256][9] ext -> [9][8][576][32] bf16 -------------
__global__ __launch_bounds__(256) void wcvt0_kernel(
    const void* __restrict__ w, const int* __restrict__ flagp,
    __hip_bfloat16* __restrict__ dst) {
  const int oc = blockIdx.x, t = threadIdx.x;
  const int isbf = *flagp;
  __shared__ float lds[2304];
  for (int idx=t; idx<2304; idx+=256)
    lds[idx] = ldin(w, (size_t)oc*2304 + idx, isbf);
  __syncthreads();
  for (int idx=t; idx<2304; idx+=256){
    int koff = idx >> 8, rem = idx & 255;
    int icb = rem >> 5, ici = rem & 31;
    dst[(((size_t)koff*8 + icb)*CC + oc)*32 + ici] = f2bf(lds[rem*9 + koff]);
  }
}

// ---- convs_w layer li [576][576][9] ext -> [9][18][576][32] bf16 ---------
// (fallback path when workspace too small for wall buffer)
__global__ __launch_bounds__(256) void wcvtL_kernel(
    const void* __restrict__ w, int li, const int* __restrict__ flagp,
    __hip_bfloat16* __restrict__ dst) {
  const int oc = blockIdx.x, t = threadIdx.x;
  const int isbf = *flagp;
  __shared__ float lds[5184];
  for (int idx=t; idx<5184; idx+=256)
    lds[idx] = ldin(w, ((size_t)li*CC + oc)*5184 + idx, isbf);
  __syncthreads();
  for (int idx=t; idx<5184; idx+=256){
    int koff = idx / 576, rem = idx - koff*576;
    int icb = rem >> 5, ici = rem & 31;
    dst[(((size_t)koff*18 + icb)*CC + oc)*32 + ici] = f2bf(lds[rem*9 + koff]);
  }
}

// ---- ALL 7 conv layers' weights, v2: vectorized + full-line writes -------
__global__ __launch_bounds__(256) void wcvtAll2_kernel(
    const void* __restrict__ w, const int* __restrict__ flagp,
    __hip_bfloat16* __restrict__ dst_base) {
  const int oc0 = blockIdx.x*2, li = blockIdx.y, t = threadIdx.x;
  const int isbf = *flagp;
  __hip_bfloat16* dst = dst_base + (size_t)li * (9u*18u*576u*32u);
  __shared__ alignas(16) __hip_bfloat16 lds[2*5184];

  if (isbf){
    const unsigned short* ws = (const unsigned short*)w;
    for (int idx=t; idx<1296; idx+=256){
      int ocl = idx/648, j = idx - ocl*648;
      *(bfrag*)(lds + ocl*5184 + j*8) =
        *(const bfrag*)(ws + ((size_t)(li*CC + oc0+ocl))*5184 + j*8);
    }
  } else {
    const float* wf = (const float*)w;
    for (int idx=t; idx<1296; idx+=256){
      int ocl = idx/648, j = idx - ocl*648;
      const float* s = wf + ((size_t)(li*CC + oc0+ocl))*5184 + j*8;
      f32x4 v0 = *(const f32x4*)(s);
      f32x4 v1 = *(const f32x4*)(s+4);
      alignas(16) __hip_bfloat16 tmp[8];
      #pragma unroll
      for (int u=0;u<4;u++){ tmp[u] = f2bf(v0[u]); tmp[4+u] = f2bf(v1[u]); }
      *(bfrag*)(lds + ocl*5184 + j*8) = *(const bfrag*)tmp;
    }
  }
  __syncthreads();

  for (int idx=t; idx<1296; idx+=256){
    int g = idx>>1, ocl = idx&1;
    int koff = g/72, r = g - koff*72;
    int icb = r>>2, q = r&3;
    const __hip_bfloat16* src = lds + ocl*5184;
    alignas(16) __hip_bfloat16 tmp[8];
    #pragma unroll
    for (int u=0;u<8;u++)
      tmp[u] = src[(icb*32 + q*8 + u)*9 + koff];
    *(bfrag*)(dst + (((size_t)koff*18 + icb)*CC + (oc0+ocl))*32 + q*8) =
        *(const bfrag*)tmp;
  }
}

// ---- epilogue for conv0 (64 ch / 4 GN groups, validated) -----------------
static __device__ __forceinline__ void epilogue_gn(
    float* s_out, float* s_stats, const f32x4 (&acc)[2][2],
    int wm, int wn, int ln, int quad, int t,
    const void* bias, int bias_off,
    const void* gamma, const void* beta, int goff,
    int nbb, int isbf, int b,
    __hip_bfloat16* __restrict__ out)
{
  __syncthreads();
  #pragma unroll
  for (int nf=0; nf<2; nf++){
    int chl = wn*32 + nf*16 + ln;
    float bv = ldin(bias, (size_t)bias_off + nbb + chl, isbf);
    #pragma unroll
    for (int mf=0; mf<2; mf++){
      #pragma unroll
      for (int r=0; r<4; r++){
        int px = wm*32 + mf*16 + quad*4 + r;
        s_out[chl*65 + px] = acc[mf][nf][r] + bv;
      }
    }
  }
  __syncthreads();
  {
    int wv = t >> 6, l = t & 63;
    float s=0.f, ss=0.f;
    for (int j=l; j<784; j+=64){
      int cq = j/49, px = j - cq*49;
      float v = s_out[(wv*16+cq)*65 + px];
      s += v; ss += v*v;
    }
    #pragma unroll
    for (int o=32;o>0;o>>=1){ s+=__shfl_down(s,o); ss+=__shfl_down(ss,o); }
    if (l==0){
      float mean=s/784.f, var=ss/784.f-mean*mean;
      s_stats[wv*2]=mean; s_stats[wv*2+1]=rsqrtf(fmaxf(var,0.f)+1e-5f);
    }
  }
  __syncthreads();
  for (int idx=t; idx<392; idx+=256){
    int px = idx>>3, ck = idx&7;
    alignas(16) __hip_bfloat16 tmp[8];
    #pragma unroll
    for (int u=0;u<8;u++){
      int chl = ck*8+u;
      int gi = chl>>4;
      float ga = ldin(gamma, (size_t)goff + nbb + chl, isbf);
      float be = ldin(beta,  (size_t)goff + nbb + chl, isbf);
      float v = (s_out[chl*65+px]-s_stats[gi*2])*s_stats[gi*2+1]*ga + be;
      tmp[u] = f2bf(fmaxf(v,0.f));
    }
    *(bfrag*)(out + ((size_t)b*64+px)*CC + nbb + ck*8) = *(const bfrag*)tmp;
  }
}

// ---- conv3x3 s1 p1 + GN + ReLU, v8 (best validated: 60.0 us/layer) -------
// flat grid 1152 = 64 b x 18 slices; sw=(id&7)*144+(id>>3) (bijective) ->
// each XCD owns ~2.25 contiguous 32-oc weight slices (FETCH 25.3->19 MB).
// Wave tile 32Mx16N, 4 waves, K-chunk 64 (9 barriers), T14 reg-prefetch.
// Structural plateau: v4 (48N), v5 (8-wave), v7 (2-wave), v9 (reg-burst)
// all regressed; v6/v8 micro-opts neutral-to-small. Keep as-is.
__global__ __launch_bounds__(256) void conv3_v8_kernel(
    const __hip_bfloat16* __restrict__ A,     // NHWC [64][64][576], px<49 valid
    const __hip_bfloat16* __restrict__ Wb,    // [9][18][576][32]
    const void* __restrict__ bias, int bias_off,
    const void* __restrict__ gamma, const void* __restrict__ beta, int goff,
    const int* __restrict__ flagp,
    __hip_bfloat16* __restrict__ out) {
  const int t = threadIdx.x;
  const int l = t & 63, w = t >> 6;
  const int wm = w & 1, wn = (w >> 1) & 1;
  const int ln = l & 15, quad = l >> 4;
  const int id = blockIdx.x;
  const int sw = (id & 7)*144 + (id >> 3);   // XCD-contiguous remap (bijective)
  const int b = sw & 63, nbb = (sw >> 6)*32;
  const int isbf = *flagp;

  __shared__ alignas(16) char smem[14400];
  __shared__ float s_stats[4];
  __hip_bfloat16* sA0 = (__hip_bfloat16*)smem;
  __hip_bfloat16* sA1 = (__hip_bfloat16*)(smem + 7200);
  float* s_out = (float*)smem;

  if (t < 16){
    bfrag z = {0,0,0,0,0,0,0,0};
    __hip_bfloat16* sb = (t<8)? sA0 : sA1;
    *(bfrag*)(sb + 49*72 + (t&7)*8) = z;
  }

  int r0a[9], r1a[9];
  {
    int p0 = wm*32 + ln, p1 = p0+16;
    int y0=p0/7, x0=p0-y0*7, y1=p1/7, x1=p1-y1*7;
    bool v0=p0<49, v1=p1<49;
    #pragma unroll
    for (int koff=0;koff<9;koff++){
      int dy=koff/3-1, dx=koff-(koff/3)*3-1;
      int sy0=y0+dy,sx0=x0+dx, sy1=y1+dy,sx1=x1+dx;
      r0a[koff] = (v0&&sy0>=0&&sy0<7&&sx0>=0&&sx0<7)? sy0*7+sx0 : 49;
      r1a[koff] = (v1&&sy1>=0&&sy1<7&&sx1>=0&&sx1<7)? sy1*7+sx1 : 49;
    }
  }

  f32x4 acc2[2];
  acc2[0] = (f32x4){0.f,0.f,0.f,0.f};
  acc2[1] = (f32x4){0.f,0.f,0.f,0.f};

  const int i0r = t>>3, is8 = (t&7)*8;
  const int i1r = i0r + 32;
  const bool has1 = (t < 136);
  const __hip_bfloat16* Ab = A + (size_t)b*64*CC;

  *(bfrag*)(sA0 + i0r*72 + is8) = *(const bfrag*)(Ab + (size_t)i0r*CC + is8);
  if (has1)
    *(bfrag*)(sA0 + i1r*72 + is8) = *(const bfrag*)(Ab + (size_t)i1r*CC + is8);
  __syncthreads();

  const int nidx = nbb + wn*16 + ln;
  const __hip_bfloat16* wbase = Wb + (size_t)nidx*32 + quad*8;
  for (int c=0; c<9; c++){
    __hip_bfloat16* curb = (c&1)? sA1 : sA0;
    bfrag rs0, rs1;
    const bool pf = (c<8);
    if (pf){
      rs0 = *(const bfrag*)(Ab + (size_t)i0r*CC + (c+1)*64 + is8);
      if (has1) rs1 = *(const bfrag*)(Ab + (size_t)i1r*CC + (c+1)*64 + is8);
    }
    #pragma unroll
    for (int koff=0;koff<9;koff++){
      const int ra0 = r0a[koff]*72 + quad*8;
      const int ra1 = r1a[koff]*72 + quad*8;
      #pragma unroll
      for (int ks=0; ks<2; ks++){
        const __hip_bfloat16* wp = wbase + (size_t)(koff*18 + c*2 + ks)*18432;
        bfrag b0 = *(const bfrag*)(wp);
        bfrag a0 = *(const bfrag*)(curb + ra0 + ks*32);
        bfrag a1 = *(const bfrag*)(curb + ra1 + ks*32);
        acc2[0] = __builtin_amdgcn_mfma_f32_16x16x32_bf16(a0, b0, acc2[0], 0,0,0);
        acc2[1] = __builtin_amdgcn_mfma_f32_16x16x32_bf16(a1, b0, acc2[1], 0,0,0);
      }
    }
    if (pf){
      __hip_bfloat16* nxtb = (c&1)? sA0 : sA1;
      *(bfrag*)(nxtb + i0r*72 + is8) = rs0;
      if (has1) *(bfrag*)(nxtb + i1r*72 + is8) = rs1;
    }
    __syncthreads();
  }

  // epilogue: 32 ch x 49 px, 2 GN groups of 16 ch
  {
    const int chl = wn*16 + ln;
    float bv = ldin(bias, (size_t)bias_off + nbb + chl, isbf);
    #pragma unroll
    for (int mf=0; mf<2; mf++)
      #pragma unroll
      for (int r=0;r<4;r++){
        int px = wm*32 + mf*16 + quad*4 + r;
        s_out[chl*65 + px] = acc2[mf][r] + bv;
      }
  }
  __syncthreads();
  {
    int wv = t >> 6, l2 = t & 63;
    if (wv < 2){
      float s=0.f, ss=0.f;
      for (int j=l2; j<784; j+=64){
        int cq = j/49, px = j - cq*49;
        float v = s_out[(wv*16+cq)*65 + px];
        s += v; ss += v*v;
      }
      #pragma unroll
      for (int o=32;o>0;o>>=1){ s+=__shfl_down(s,o); ss+=__shfl_down(ss,o); }
      if (l2==0){
        float mean=s/784.f, var=ss/784.f-mean*mean;
        s_stats[wv*2]=mean; s_stats[wv*2+1]=rsqrtf(fmaxf(var,0.f)+1e-5f);
      }
    }
  }
  __syncthreads();
  if (t < 196){
    int px = t>>2, ck = t&3;
    alignas(16) __hip_bfloat16 tmp[8];
    #pragma unroll
    for (int u=0;u<8;u++){
      int chl = ck*8+u;
      int gi = chl>>4;
      float ga = ldin(gamma, (size_t)goff + nbb + chl, isbf);
      float be = ldin(beta,  (size_t)goff + nbb + chl, isbf);
      float v = (s_out[chl*65+px]-s_stats[gi*2])*s_stats[gi*2+1]*ga + be;
      tmp[u] = f2bf(fmaxf(v,0.f));
    }
    *(bfrag*)(out + ((size_t)b*64+px)*CC + nbb + ck*8) = *(const bfrag*)tmp;
  }
}

// ---- conv0 3x3 s2 p1 + GN + ReLU, chunked LDS A, MFMA (validated) --------
__global__ __launch_bounds__(256) void conv0_fused_kernel(
    const __hip_bfloat16* __restrict__ A,     // NHWC [64][196][256]
    const __hip_bfloat16* __restrict__ Wb,    // [9][8][576][32]
    const void* __restrict__ bias,
    const void* __restrict__ gamma, const void* __restrict__ beta,
    const int* __restrict__ flagp,
    __hip_bfloat16* __restrict__ out) {       // NHWC [64][64][576]
  const int t = threadIdx.x;
  const int l = t & 63, w = t >> 6;
  const int wm = w & 1, wn = w >> 1;
  const int ln = l & 15, quad = l >> 4;
  const int b = blockIdx.x, nbb = blockIdx.y*64;

  __shared__ alignas(16) __hip_bfloat16 sC[197*40];
  __shared__ alignas(16) float s_out_arr[64*65];
  __shared__ float s_stats[8];

  if (t < 4){
    bfrag z = {0,0,0,0,0,0,0,0};
    *(bfrag*)(sC + 196*40 + t*8) = z;
  }

  int yy[2], xx[2]; bool pv[2];
  #pragma unroll
  for (int mf=0; mf<2; mf++){
    int p = wm*32 + mf*16 + ln;
    pv[mf] = p<49; yy[mf]=p/7; xx[mf]=p-yy[mf]*7;
  }

  f32x4 acc[2][2];
  #pragma unroll
  for (int i=0;i<2;i++)
    #pragma unroll
    for (int j=0;j<2;j++) acc[i][j] = (f32x4){0.f,0.f,0.f,0.f};

  for (int icb=0; icb<8; icb++){
    __syncthreads();
    for (int idx=t*8; idx<6272; idx+=2048){
      int px = idx>>5, ic = idx&31;
      *(bfrag*)(sC + px*40 + ic) = *(const bfrag*)(A + ((size_t)b*196+px)*256 + icb*32 + ic);
    }
    __syncthreads();
    for (int koff=0; koff<9; koff++){
      const int dy = koff/3 - 1, dx = koff - (koff/3)*3 - 1;
      int sy0=2*yy[0]+dy, sx0=2*xx[0]+dx;
      int r0 = (pv[0]&&sy0>=0&&sy0<14&&sx0>=0&&sx0<14) ? sy0*14+sx0 : 196;
      int sy1=2*yy[1]+dy, sx1=2*xx[1]+dx;
      int r1 = (pv[1]&&sy1>=0&&sy1<14&&sx1>=0&&sx1<14) ? sy1*14+sx1 : 196;
      bfrag a0 = *(const bfrag*)(sC + r0*40 + quad*8);
      bfrag a1 = *(const bfrag*)(sC + r1*40 + quad*8);
      const __hip_bfloat16* wp = Wb + ((size_t)(koff*8+icb)*576 + nbb + wn*32 + ln)*32 + quad*8;
      bfrag b0 = *(const bfrag*)(wp);
      bfrag b1 = *(const bfrag*)(wp + 16*32);
      acc[0][0] = __builtin_amdgcn_mfma_f32_16x16x32_bf16(a0, b0, acc[0][0], 0,0,0);
      acc[1][0] = __builtin_amdgcn_mfma_f32_16x16x32_bf16(a1, b0, acc[1][0], 0,0,0);
      acc[0][1] = __builtin_amdgcn_mfma_f32_16x16x32_bf16(a0, b1, acc[0][1], 0,0,0);
      acc[1][1] = __builtin_amdgcn_mfma_f32_16x16x32_bf16(a1, b1, acc[1][1], 0,0,0);
    }
  }

  epilogue_gn(s_out_arr, s_stats, acc, wm, wn, ln, quad, t,
              bias, 0, gamma, beta, 0, nbb, *flagp, b, out);
}

// ---- depthwise 5x5 per edge: F NHWC -> Y[e][(b*49+px)][64] bf16 ----------
__global__ __launch_bounds__(256) void dw_edge_kernel(
    const __hip_bfloat16* __restrict__ F,
    const void* __restrict__ dw_w,   // [24][64][25]
    const void* __restrict__ dw_b,   // [24][64]
    const int* __restrict__ flagp,
    __hip_bfloat16* __restrict__ Y) {
  const int b = blockIdx.x, e = blockIdx.y, t = threadIdx.x;
  const int isbf = *flagp;
  const int src = EDGE_SRC_C[e];
  __shared__ alignas(16) __hip_bfloat16 sA[50*72];   // 49 px rows + zero row
  for (int idx=t; idx<400; idx+=256){
    if (idx < 392){
      int px = idx>>3, ic = (idx&7)*8;
      *(bfrag*)(sA + px*72 + ic) = *(const bfrag*)(F + ((size_t)b*64+px)*CC + src*64 + ic);
    } else {
      bfrag z = {0,0,0,0,0,0,0,0};
      *(bfrag*)(sA + 49*72 + (idx-392)*8) = z;
    }
  }
  __syncthreads();
  const int ch = t & 63, wv = t >> 6;
  float wd[25];
  #pragma unroll
  for (int j=0;j<25;j++) wd[j] = ldin(dw_w, (size_t)e*1600 + ch*25 + j, isbf);
  float dwb = ldin(dw_b, e*64 + ch, isbf);
  for (int px=wv; px<49; px+=4){
    int oy=px/7, ox=px-oy*7;
    float a = dwb;
    #pragma unroll
    for (int u=0;u<5;u++){
      int py = oy+u-2;
      bool vy = (py>=0)&&(py<7);
      #pragma unroll
      for (int v=0;v<5;v++){
        int pxx = ox+v-2;
        int r = (vy && pxx>=0 && pxx<7) ? py*7+pxx : 49;
        a += bf2f(sA[r*72 + ch]) * wd[u*5+v];
      }
    }
    Y[((size_t)(e*64+b)*49 + px)*64 + ch] = f2bf(a);
  }
}

// ---- pack pointwise weights to bf16 [24][64oc][64ic] ---------------------
__global__ __launch_bounds__(256) void pwpack_kernel(
    const void* __restrict__ pw_fo, const void* __restrict__ pw_so,
    const int* __restrict__ flagp,
    __hip_bfloat16* __restrict__ dfo, __hip_bfloat16* __restrict__ dso) {
  const int e = blockIdx.x, t = threadIdx.x;
  const int isbf = *flagp;
  for (int idx=t; idx<4096; idx+=256){
    dfo[(size_t)e*4096+idx] = f2bf(ldin(pw_fo, (size_t)e*4096+idx, isbf));
    dso[(size_t)e*4096+idx] = f2bf(ldin(pw_so, (size_t)e*4096+idx, isbf));
  }
}

// ---- pointwise + segment-sum via MFMA: out = base + sum_e Y_e @ pw_e^T ---
__global__ __launch_bounds__(256) void pw_seg_kernel(
    const __hip_bfloat16* __restrict__ Y,     // [24][3136][64]
    const __hip_bfloat16* __restrict__ base,  // NHWC [64][64][576]
    const __hip_bfloat16* __restrict__ pwb,   // [24][64oc][64ic] bf16
    const void* __restrict__ pw_b,            // [24][64] ext
    const int* __restrict__ flagp,
    __hip_bfloat16* __restrict__ out) {       // NHWC
  const int t = threadIdx.x, l = t & 63, w = t >> 6;
  const int wm = w & 1, wn = w >> 1;
  const int ln = l & 15, quad = l >> 4;
  const int dst = blockIdx.y;
  const int mt = blockIdx.x*64 + wm*32;
  const int m0 = mt + ln, m1 = m0 + 16;

  f32x4 acc[2][2];
  #pragma unroll
  for (int i=0;i<2;i++)
    #pragma unroll
    for (int j=0;j<2;j++) acc[i][j] = (f32x4){0.f,0.f,0.f,0.f};

  const int eoff = EDGE_OFF_C[dst], ecnt = EDGE_CNT_C[dst];
  for (int k=0;k<ecnt;k++){
    const __hip_bfloat16* Ye = Y + (size_t)(eoff+k)*3136*64;
    const __hip_bfloat16* pe = pwb + (size_t)(eoff+k)*4096;
    #pragma unroll
    for (int ks=0; ks<2; ks++){
      const int kq = ks*32 + quad*8;
      bfrag a0 = *(const bfrag*)(Ye + (size_t)m0*64 + kq);
      bfrag a1 = *(const bfrag*)(Ye + (size_t)m1*64 + kq);
      bfrag b0 = *(const bfrag*)(pe + (wn*32+ln)*64 + kq);
      bfrag b1 = *(const bfrag*)(pe + (wn*32+ln+16)*64 + kq);
      acc[0][0] = __builtin_amdgcn_mfma_f32_16x16x32_bf16(a0, b0, acc[0][0], 0,0,0);
      acc[1][0] = __builtin_amdgcn_mfma_f32_16x16x32_bf16(a1, b0, acc[1][0], 0,0,0);
      acc[0][1] = __builtin_amdgcn_mfma_f32_16x16x32_bf16(a0, b1, acc[0][1], 0,0,0);
      acc[1][1] = __builtin_amdgcn_mfma_f32_16x16x32_bf16(a1, b1, acc[1][1], 0,0,0);
    }
  }

  const int isbf = *flagp;
  #pragma unroll
  for (int nf=0; nf<2; nf++){
    int n = wn*32 + nf*16 + ln;
    float pbs = 0.f;
    for (int k=0;k<ecnt;k++) pbs += ldin(pw_b, (size_t)(eoff+k)*64 + n, isbf);
    #pragma unroll
    for (int mf=0; mf<2; mf++){
      #pragma unroll
      for (int r=0; r<4; r++){
        int m = mt + mf*16 + quad*4 + r;
        int bb = m/49, px = m - bb*49;
        size_t oi = ((size_t)bb*64 + px)*CC + dst*64 + n;
        out[oi] = f2bf(bf2f(base[oi]) + acc[mf][nf][r] + pbs);
      }
    }
  }
}

// ---- up1_w [576][64][16] ext -> wpack [9][16tap][64oc][64ic] bf16 --------
__global__ __launch_bounds__(256) void wpack_dc1_kernel(
    const void* __restrict__ w1, const int* __restrict__ flagp,
    __hip_bfloat16* __restrict__ dst) {
  const int gtap = blockIdx.x, t = threadIdx.x;
  const int isbf = *flagp;
  const int g = gtap >> 4, tap = gtap & 15;
  for (int idx=t; idx<64*64; idx+=256){
    int oc = idx >> 6, ic = idx & 63;
    dst[((size_t)gtap*64 + oc)*64 + ic] =
        f2bf(ldin(w1, ((size_t)(g*64+ic)*64 + oc)*16 + tap, isbf));
  }
}

// ---- deconv1 via parity-class MFMA: H NHWC -> mid NHWC [64][196][576] ----
// ConvTranspose2d(k=4,s=2,p=1): output pixel (oy,ox) uses exactly 2x2 taps
// with ky parity == (oy+1)&1, kx parity == (ox+1)&1. Grid (49 Mtiles, 4
// classes, 9 groups); M = 64b*49px per class tiles exactly into 49x64.
// NOTE: 64 consecutive m = b*49+p rows span up to THREE batches; three
// batch slices staged (slice 2 zero-filled when b0+2 > 63). Pad-72 stride.
__global__ __launch_bounds__(256) void dc1_cls_kernel(
    const __hip_bfloat16* __restrict__ H,    // NHWC [64][64(px pad)][576]
    const __hip_bfloat16* __restrict__ Wp,   // [(g*16+tap)][oc][ic]
    const void* __restrict__ b1,
    const int* __restrict__ flagp,
    __hip_bfloat16* __restrict__ mid) {
  const int t = threadIdx.x;
  const int l = t & 63, w = t >> 6;
  const int wm = w & 1, wn = w >> 1;
  const int ln = l & 15, quad = l >> 4;
  const int Mt = blockIdx.x;        // 0..48, 64 rows of (b*49+p)
  const int cls = blockIdx.y;       // ry*2+rx
  const int g = blockIdx.z;
  const int ry = cls >> 1, rx = cls & 1;
  const int b0 = (Mt*64)/49;        // block spans b0 .. b0+2 (guarded)

  __shared__ alignas(16) __hip_bfloat16 sX[3*50*72];  // [bloc][px(+zero)][ic]

  {
    const bfrag z = {0,0,0,0,0,0,0,0};
    for (int idx=t; idx<1200; idx+=256){
      int bi = idx/400, rem = idx - bi*400;
      int p = rem>>3, ch = (rem&7)*8;
      bfrag v = z;
      if (p < 49 && (b0+bi) < 64)
        v = *(const bfrag*)(H + ((size_t)((b0+bi)*64) + p)*CC + g*64 + ch);
      *(bfrag*)(sX + (bi*50+p)*72 + ch) = v;
    }
  }

  // per-lane A row offsets for the 4 taps of this class
  int aoff[2][4];
  #pragma unroll
  for (int mf=0; mf<2; mf++){
    int m = Mt*64 + wm*32 + mf*16 + ln;
    int b = m/49, p = m - b*49;
    int py = p/7, pxx = p - py*7;
    int bloc = b - b0;
    #pragma unroll
    for (int kyi=0;kyi<2;kyi++){
      int iy = py + ry - kyi;
      bool vy = (iy>=0)&&(iy<7);
      #pragma unroll
      for (int kxi=0;kxi<2;kxi++){
        int ix = pxx + rx - kxi;
        int r = (vy && ix>=0 && ix<7) ? iy*7+ix : 49;
        aoff[mf][kyi*2+kxi] = (bloc*50 + r)*72 + quad*8;
      }
    }
  }

  f32x4 acc[2][2];
  #pragma unroll
  for (int i=0;i<2;i++)
    #pragma unroll
    for (int j=0;j<2;j++) acc[i][j] = (f32x4){0.f,0.f,0.f,0.f};

  __syncthreads();

  const int ky0 = 1-ry, kx0 = 1-rx;
  #pragma unroll
  for (int kyi=0;kyi<2;kyi++){
    #pragma unroll
    for (int kxi=0;kxi<2;kxi++){
      const int tap = (ky0+2*kyi)*4 + (kx0+2*kxi);
      const __hip_bfloat16* wb =
          Wp + ((size_t)(g*16+tap)*64 + wn*32 + ln)*64 + quad*8;
      const int ao0 = aoff[0][kyi*2+kxi], ao1 = aoff[1][kyi*2+kxi];
      #pragma unroll
      for (int half=0; half<2; half++){
        bfrag a0 = *(const bfrag*)(sX + ao0 + half*32);
        bfrag a1 = *(const bfrag*)(sX + ao1 + half*32);
        bfrag w0 = *(const bfrag*)(wb + half*32);
        bfrag w1 = *(const bfrag*)(wb + 16*64 + half*32);
        acc[0][0] = __builtin_amdgcn_mfma_f32_16x16x32_bf16(a0, w0, acc[0][0], 0,0,0);
        acc[1][0] = __builtin_amdgcn_mfma_f32_16x16x32_bf16(a1, w0, acc[1][0], 0,0,0);
        acc[0][1] = __builtin_amdgcn_mfma_f32_16x16x32_bf16(a0, w1, acc[0][1], 0,0,0);
        acc[1][1] = __builtin_amdgcn_mfma_f32_16x16x32_bf16(a1, w1, acc[1][1], 0,0,0);
      }
    }
  }

  const int isbf = *flagp;
  size_t ob[2][4];
  #pragma unroll
  for (int mf=0;mf<2;mf++){
    #pragma unroll
    for (int r=0;r<4;r++){
      int m = Mt*64 + wm*32 + mf*16 + quad*4 + r;
      int b = m/49, p = m - b*49;
      int py = p/7, pxx = p - py*7;
      int oy = 2*py + ry, ox = 2*pxx + rx;
      ob[mf][r] = ((size_t)b*196 + oy*14 + ox)*CC + g*64;
    }
  }
  #pragma unroll
  for (int nf=0;nf<2;nf++){
    int n = wn*32 + nf*16 + ln;
    float bv = ldin(b1, g*64 + n, isbf);
    #pragma unroll
    for (int mf=0;mf<2;mf++){
      #pragma unroll
      for (int r=0;r<4;r++)
        mid[ob[mf][r] + n] = f2bf(acc[mf][nf][r] + bv);
    }
  }
}

// ---- fused GN(9)+ReLU+deconv2, v2: ONE block per (b,g), stats once -------
// Removes the z-split (which duplicated the 25 KB stats read + reduction).
// LDS: s_mid [64ch][197] bf16 (25.2 KB) + s_w2 4.3 KB -> 5 blocks/CU.
// Stats pass vectorized (bfrag, 16B/lane). Grid (64, 9).
__global__ __launch_bounds__(256) void dc2gn_kernel(
    const __hip_bfloat16* __restrict__ mid,   // [64][196][576] (bias only)
    const void* __restrict__ gamma, const void* __restrict__ beta,
    const void* __restrict__ w2,
    const void* __restrict__ b2,
    const int* __restrict__ flagp,
    void* __restrict__ outp,
    size_t out_elem_off) {
  const int isbf = *flagp;
  const int b=blockIdx.x, g=blockIdx.y, t=threadIdx.x;
  const int c = t & 63;
  __shared__ __hip_bfloat16 s_mid[64*197];   // [c][196 px + pad]
  __shared__ float s_w2[64][17];
  __shared__ float red[8]; __shared__ float stats[2];
  const __hip_bfloat16* mbase = mid + (size_t)b*196*CC + g*64;

  // group stats over 196px x 64ch, vectorized 8-wide (1568 bfrag slots)
  {
    float s=0.f, ss=0.f;
    for (int idx=t; idx<1568; idx+=256){
      int ipx = idx>>3, c8 = (idx&7)*8;
      bfrag v8 = *(const bfrag*)(mbase + (size_t)ipx*CC + c8);
      #pragma unroll
      for (int u=0;u<8;u++){
        float v = bf2f(((const __hip_bfloat16*)&v8)[u]);
        s += v; ss += v*v;
      }
    }
    #pragma unroll
    for (int o=32;o>0;o>>=1){ s+=__shfl_down(s,o); ss+=__shfl_down(ss,o); }
    int wid=t>>6;
    if ((t&63)==0){ red[wid]=s; red[4+wid]=ss; }
  }
  for (int idx=t; idx<1024; idx+=256)
    s_w2[idx>>4][idx&15] = ldin(w2, (g*SPC + (idx>>4))*16 + (idx&15), isbf);
  __syncthreads();
  if (t==0){
    float S=red[0]+red[1]+red[2]+red[3];
    float SS=red[4]+red[5]+red[6]+red[7];
    float mean=S/12544.f, var=SS/12544.f-mean*mean;
    stats[0]=mean; stats[1]=rsqrtf(fmaxf(var,0.f)+1e-5f);
  }
  __syncthreads();
  const float mean=stats[0], inv=stats[1];
  {
    float ga = ldin(gamma, g*SPC+c, isbf), be = ldin(beta, g*SPC+c, isbf);
    for (int idx=t; idx<12544; idx+=256){
      int pl = idx>>6;                   // c = idx&63 == t&63 (stride 256)
      float v = (bf2f(mbase[(size_t)pl*CC + c])-mean)*inv*ga + be;
      s_mid[c*197 + pl] = f2bf(fmaxf(v, 0.f));
    }
  }
  __syncthreads();
  float b2v = ldin(b2, g, isbf);
  for (int p=t; p<784; p+=256){
    int oy = p/28, ox = p - oy*28;
    float a = b2v;
    for (int cc=0; cc<64; cc++){
      #pragma unroll
      for (int kyi=0;kyi<2;kyi++){
        int ky=((oy+1)&1)+2*kyi; int ny=oy+1-ky;
        if (ny>=0){
          int iy=ny>>1;
          if (iy<14){
            #pragma unroll
            for (int kxi=0;kxi<2;kxi++){
              int kx=((ox+1)&1)+2*kxi; int nx=ox+1-kx;
              if (nx>=0){
                int ix=nx>>1;
                if (ix<14) a += bf2f(s_mid[cc*197 + iy*14 + ix])*s_w2[cc][ky*4+kx];
              }
            }
          }
        }
      }
    }
    size_t oidx = out_elem_off + ((size_t)b*NGR+g)*HW28 + oy*28 + ox;
    if (isbf) ((__hip_bfloat16*)outp)[oidx] = f2bf(a);
    else      ((float*)outp)[oidx] = a;
  }
}

extern "C" void kernel_launch(void* const* d_in, const int* in_sizes, int n_in,
                              void* d_out, int out_size, void* d_ws, size_t ws_size,
                              hipStream_t stream) {
  const void* x        = d_in[0];
  const void* convs_w0 = d_in[1];
  const void* convs_b0 = d_in[2];
  const void* convs_w  = d_in[3];
  const void* convs_b  = d_in[4];
  const void* gn_gamma = d_in[5];
  const void* gn_beta  = d_in[6];
  const void* fo_dw_w  = d_in[7];
  const void* fo_dw_b  = d_in[8];
  const void* fo_pw_w  = d_in[9];
  const void* fo_pw_b  = d_in[10];
  const void* so_dw_w  = d_in[11];
  const void* so_dw_b  = d_in[12];
  const void* so_pw_w  = d_in[13];
  const void* so_pw_b  = d_in[14];
  const void* up1_w    = d_in[15];
  const void* up1_b    = d_in[16];
  const void* sbn_g    = d_in[17];
  const void* sbn_b    = d_in[18];
  const void* up2_w    = d_in[19];
  const void* up2_b    = d_in[20];
  (void)in_sizes; (void)n_in; (void)out_size;

  int* flag = (int*)d_ws;
  char* wsb = (char*)d_ws + 16;
  __hip_bfloat16* act0   = (__hip_bfloat16*)(wsb);
  __hip_bfloat16* wbuf   = (__hip_bfloat16*)(wsb + 6422528);
  __hip_bfloat16* actA   = (__hip_bfloat16*)(wsb + 12394496);
  __hip_bfloat16* actB   = (__hip_bfloat16*)(wsb + 17113088);
  __hip_bfloat16* bufF   = (__hip_bfloat16*)(wsb + 21831680);
  __hip_bfloat16* secN   = (__hip_bfloat16*)(wsb + 26550272);
  __hip_bfloat16* wpack  = (__hip_bfloat16*)(wsb + 31268864);
  __hip_bfloat16* pwbF   = (__hip_bfloat16*)(wsb + 32448512);
  __hip_bfloat16* pwbS   = (__hip_bfloat16*)(wsb + 32645120);
  __hip_bfloat16* Y      = (__hip_bfloat16*)(wsb);
  __hip_bfloat16* mid    = (__hip_bfloat16*)(wsb);

  // merged weight-conversion buffer (7 layers), beyond all live buffers
  const size_t WL_ELEMS = (size_t)9*18*576*32;        // elems per layer
  const size_t wall_off = 33u*1024u*1024u;            // byte offset into wsb
  const bool bigws = ws_size >= 16 + wall_off + 7*WL_ELEMS*sizeof(__hip_bfloat16);
  __hip_bfloat16* wall = (__hip_bfloat16*)(wsb + wall_off);

  detect_kernel<<<1, 1, 0, stream>>>((const unsigned short*)x, flag);

  if (bigws)
    wcvtAll2_kernel<<<dim3(288,7), 256, 0, stream>>>(convs_w, flag, wall);

  xcvt_kernel<<<dim3(BB,8,7), 256, 0, stream>>>(x, flag, act0);
  wcvt0_kernel<<<CC, 256, 0, stream>>>(convs_w0, flag, wbuf);
  conv0_fused_kernel<<<dim3(64,9), 256, 0, stream>>>(
      act0, wbuf, convs_b0, gn_gamma, gn_beta, flag, actA);

  __hip_bfloat16* cur = actA; __hip_bfloat16* nxt = actB;
  for (int i=0;i<7;i++){
    const __hip_bfloat16* wb_i;
    if (bigws){
      wb_i = wall + (size_t)i*WL_ELEMS;
    } else {
      wcvtL_kernel<<<CC, 256, 0, stream>>>(convs_w, i, flag, wbuf);
      wb_i = wbuf;
    }
    conv3_v8_kernel<<<1152, 256, 0, stream>>>(
        cur, wb_i, convs_b, i*CC, gn_gamma, gn_beta, (i+1)*CC, flag, nxt);
    __hip_bfloat16* tmp=cur; cur=nxt; nxt=tmp;
  }
  // cur == actB (h, NHWC)

  wpack_dc1_kernel<<<144, 256, 0, stream>>>(up1_w, flag, wpack);
  pwpack_kernel<<<24, 256, 0, stream>>>(fo_pw_w, so_pw_w, flag, pwbF, pwbS);

  // edge pass 1: first = h + seg(pw(dw(h)))
  dw_edge_kernel<<<dim3(BB,24), 256, 0, stream>>>(cur, fo_dw_w, fo_dw_b, flag, Y);
  pw_seg_kernel<<<dim3(49,NGR), 256, 0, stream>>>(Y, cur, pwbF, fo_pw_b, flag, bufF);
  // edge pass 2: second = h + seg(pw(dw(first)))
  dw_edge_kernel<<<dim3(BB,24), 256, 0, stream>>>(bufF, so_dw_w, so_dw_b, flag, Y);
  pw_seg_kernel<<<dim3(49,NGR), 256, 0, stream>>>(Y, cur, pwbS, so_pw_b, flag, secN);

  // head 1 (input h = cur, NHWC)
  dc1_cls_kernel<<<dim3(49,4,NGR), 256, 0, stream>>>(cur, wpack, up1_b, flag, mid);
  dc2gn_kernel<<<dim3(BB,NGR), 256, 0, stream>>>(mid, sbn_g, sbn_b, up2_w, up2_b, flag, d_out, 0);
  // head 2 (input secN, NHWC)
  dc1_cls_kernel<<<dim3(49,4,NGR), 256, 0, stream>>>(secN, wpack, up1_b, flag, mid);
  dc2gn_kernel<<<dim3(BB,NGR), 256, 0, stream>>>(mid, sbn_g, sbn_b, up2_w, up2_b, flag, d_out, (size_t)BB*NGR*HW28);
}

// Round 13
// 869.890 us; speedup vs baseline: 1.0607x; 1.0217x over previous
//
#include <hip/hip_runtime.h>
#include <hip/hip_bf16.h>

#define BB 64
#define CIN 256
#define CC 576
#define NGR 9
#define SPC 64
#define HW7 49
#define HW14 196
#define HW28 784

__device__ __constant__ int EDGE_SRC_C[24] = {1,3, 0,2,4, 1,5, 0,4,6, 1,3,5,7, 2,4,8, 3,7, 4,6,8, 5,7};
__device__ __constant__ int EDGE_OFF_C[9]  = {0,2,5,7,10,14,17,19,22};
__device__ __constant__ int EDGE_CNT_C[9]  = {2,3,2,3,4,3,2,3,2};

static __device__ __forceinline__ float bf2f(__hip_bfloat16 v){ return __bfloat162float(v); }
static __device__ __forceinline__ __hip_bfloat16 f2bf(float v){ return __float2bfloat16(v); }
static __device__ __forceinline__ float ldin(const void* p, size_t i, int isbf){
  return isbf ? bf2f(((const __hip_bfloat16*)p)[i]) : ((const float*)p)[i];
}

using bfrag = __attribute__((ext_vector_type(8))) short;
using f32x4 = __attribute__((ext_vector_type(4))) float;

// ---- dtype detector ------------------------------------------------------
__global__ void detect_kernel(const unsigned short* xs, int* flag) {
  if (threadIdx.x==0 && blockIdx.x==0) {
    int plaus = 0;
    for (int i=0;i<64;i++){
      unsigned short u = xs[2*i];
      int e = (u>>7)&0xFF;
      if (e>=100 && e<=140) plaus++;
    }
    *flag = (plaus >= 40) ? 1 : 0;
  }
}

// ---- x: [64,256,14,14] ext -> act0 NHWC bf16 [64][196][256] --------------
__global__ __launch_bounds__(256) void xcvt_kernel(
    const void* __restrict__ x, const int* __restrict__ flagp,
    __hip_bfloat16* __restrict__ act0) {
  const int b = blockIdx.x, icb = blockIdx.y, pxb = blockIdx.z, t = threadIdx.x;
  const int isbf = *flagp;
  __shared__ float lds[32][29];
  for (int idx=t; idx<32*28; idx+=256){
    int i = idx/28, j = idx - i*28;
    lds[i][j] = ldin(x, ((size_t)b*CIN + icb*32+i)*HW14 + pxb*28 + j, isbf);
  }
  __syncthreads();
  for (int idx=t; idx<28*32; idx+=256){
    int j = idx >> 5, i = idx & 31;
    act0[((size_t)b*HW14 + pxb*28 + j)*CIN + icb*32 + i] = f2bf(lds[i][j]);
  }
}

// ---- conv0 weights [576][256][9] ext -> [9][8][576][32] bf16 -------------
__global__ __launch_bounds__(256) void wcvt0_kernel(
    const void* __restrict__ w, const int* __restrict__ flagp,
    __hip_bfloat16* __restrict__ dst) {
  const int oc = blockIdx.x, t = threadIdx.x;
  const int isbf = *flagp;
  __shared__ float lds[2304];
  for (int idx=t; idx<2304; idx+=256)
    lds[idx] = ldin(w, (size_t)oc*2304 + idx, isbf);
  __syncthreads();
  for (int idx=t; idx<2304; idx+=256){
    int koff = idx >> 8, rem = idx & 255;
    int icb = rem >> 5, ici = rem & 31;
    dst[(((size_t)koff*8 + icb)*CC + oc)*32 + ici] = f2bf(lds[rem*9 + koff]);
  }
}

// ---- convs_w layer li [576][576][9] ext -> [9][18][576][32] bf16 ---------
// (fallback path when workspace too small for wall buffer)
__global__ __launch_bounds__(256) void wcvtL_kernel(
    const void* __restrict__ w, int li, const int* __restrict__ flagp,
    __hip_bfloat16* __restrict__ dst) {
  const int oc = blockIdx.x, t = threadIdx.x;
  const int isbf = *flagp;
  __shared__ float lds[5184];
  for (int idx=t; idx<5184; idx+=256)
    lds[idx] = ldin(w, ((size_t)li*CC + oc)*5184 + idx, isbf);
  __syncthreads();
  for (int idx=t; idx<5184; idx+=256){
    int koff = idx / 576, rem = idx - koff*576;
    int icb = rem >> 5, ici = rem & 31;
    dst[(((size_t)koff*18 + icb)*CC + oc)*32 + ici] = f2bf(lds[rem*9 + koff]);
  }
}

// ---- ALL 7 conv layers' weights, v2: vectorized + full-line writes -------
__global__ __launch_bounds__(256) void wcvtAll2_kernel(
    const void* __restrict__ w, const int* __restrict__ flagp,
    __hip_bfloat16* __restrict__ dst_base) {
  const int oc0 = blockIdx.x*2, li = blockIdx.y, t = threadIdx.x;
  const int isbf = *flagp;
  __hip_bfloat16* dst = dst_base + (size_t)li * (9u*18u*576u*32u);
  __shared__ alignas(16) __hip_bfloat16 lds[2*5184];

  if (isbf){
    const unsigned short* ws = (const unsigned short*)w;
    for (int idx=t; idx<1296; idx+=256){
      int ocl = idx/648, j = idx - ocl*648;
      *(bfrag*)(lds + ocl*5184 + j*8) =
        *(const bfrag*)(ws + ((size_t)(li*CC + oc0+ocl))*5184 + j*8);
    }
  } else {
    const float* wf = (const float*)w;
    for (int idx=t; idx<1296; idx+=256){
      int ocl = idx/648, j = idx - ocl*648;
      const float* s = wf + ((size_t)(li*CC + oc0+ocl))*5184 + j*8;
      f32x4 v0 = *(const f32x4*)(s);
      f32x4 v1 = *(const f32x4*)(s+4);
      alignas(16) __hip_bfloat16 tmp[8];
      #pragma unroll
      for (int u=0;u<4;u++){ tmp[u] = f2bf(v0[u]); tmp[4+u] = f2bf(v1[u]); }
      *(bfrag*)(lds + ocl*5184 + j*8) = *(const bfrag*)tmp;
    }
  }
  __syncthreads();

  for (int idx=t; idx<1296; idx+=256){
    int g = idx>>1, ocl = idx&1;
    int koff = g/72, r = g - koff*72;
    int icb = r>>2, q = r&3;
    const __hip_bfloat16* src = lds + ocl*5184;
    alignas(16) __hip_bfloat16 tmp[8];
    #pragma unroll
    for (int u=0;u<8;u++)
      tmp[u] = src[(icb*32 + q*8 + u)*9 + koff];
    *(bfrag*)(dst + (((size_t)koff*18 + icb)*CC + (oc0+ocl))*32 + q*8) =
        *(const bfrag*)tmp;
  }
}

// ---- epilogue for conv0 (64 ch / 4 GN groups, validated) -----------------
static __device__ __forceinline__ void epilogue_gn(
    float* s_out, float* s_stats, const f32x4 (&acc)[2][2],
    int wm, int wn, int ln, int quad, int t,
    const void* bias, int bias_off,
    const void* gamma, const void* beta, int goff,
    int nbb, int isbf, int b,
    __hip_bfloat16* __restrict__ out)
{
  __syncthreads();
  #pragma unroll
  for (int nf=0; nf<2; nf++){
    int chl = wn*32 + nf*16 + ln;
    float bv = ldin(bias, (size_t)bias_off + nbb + chl, isbf);
    #pragma unroll
    for (int mf=0; mf<2; mf++){
      #pragma unroll
      for (int r=0; r<4; r++){
        int px = wm*32 + mf*16 + quad*4 + r;
        s_out[chl*65 + px] = acc[mf][nf][r] + bv;
      }
    }
  }
  __syncthreads();
  {
    int wv = t >> 6, l = t & 63;
    float s=0.f, ss=0.f;
    for (int j=l; j<784; j+=64){
      int cq = j/49, px = j - cq*49;
      float v = s_out[(wv*16+cq)*65 + px];
      s += v; ss += v*v;
    }
    #pragma unroll
    for (int o=32;o>0;o>>=1){ s+=__shfl_down(s,o); ss+=__shfl_down(ss,o); }
    if (l==0){
      float mean=s/784.f, var=ss/784.f-mean*mean;
      s_stats[wv*2]=mean; s_stats[wv*2+1]=rsqrtf(fmaxf(var,0.f)+1e-5f);
    }
  }
  __syncthreads();
  for (int idx=t; idx<392; idx+=256){
    int px = idx>>3, ck = idx&7;
    alignas(16) __hip_bfloat16 tmp[8];
    #pragma unroll
    for (int u=0;u<8;u++){
      int chl = ck*8+u;
      int gi = chl>>4;
      float ga = ldin(gamma, (size_t)goff + nbb + chl, isbf);
      float be = ldin(beta,  (size_t)goff + nbb + chl, isbf);
      float v = (s_out[chl*65+px]-s_stats[gi*2])*s_stats[gi*2+1]*ga + be;
      tmp[u] = f2bf(fmaxf(v,0.f));
    }
    *(bfrag*)(out + ((size_t)b*64+px)*CC + nbb + ck*8) = *(const bfrag*)tmp;
  }
}

// ---- conv3x3 s1 p1 + GN + ReLU, v8 (best validated: 60.0 us/layer) -------
// flat grid 1152 = 64 b x 18 slices; sw=(id&7)*144+(id>>3) (bijective) ->
// each XCD owns ~2.25 contiguous 32-oc weight slices (FETCH 25.3->19 MB).
// Wave tile 32Mx16N, 4 waves, K-chunk 64 (9 barriers), T14 reg-prefetch.
// Structural plateau: v4 (48N), v5 (8-wave), v7 (2-wave), v9 (reg-burst)
// all regressed; v6/v8 micro-opts neutral-to-small. Keep as-is.
__global__ __launch_bounds__(256) void conv3_v8_kernel(
    const __hip_bfloat16* __restrict__ A,     // NHWC [64][64][576], px<49 valid
    const __hip_bfloat16* __restrict__ Wb,    // [9][18][576][32]
    const void* __restrict__ bias, int bias_off,
    const void* __restrict__ gamma, const void* __restrict__ beta, int goff,
    const int* __restrict__ flagp,
    __hip_bfloat16* __restrict__ out) {
  const int t = threadIdx.x;
  const int l = t & 63, w = t >> 6;
  const int wm = w & 1, wn = (w >> 1) & 1;
  const int ln = l & 15, quad = l >> 4;
  const int id = blockIdx.x;
  const int sw = (id & 7)*144 + (id >> 3);   // XCD-contiguous remap (bijective)
  const int b = sw & 63, nbb = (sw >> 6)*32;
  const int isbf = *flagp;

  __shared__ alignas(16) char smem[14400];
  __shared__ float s_stats[4];
  __hip_bfloat16* sA0 = (__hip_bfloat16*)smem;
  __hip_bfloat16* sA1 = (__hip_bfloat16*)(smem + 7200);
  float* s_out = (float*)smem;

  if (t < 16){
    bfrag z = {0,0,0,0,0,0,0,0};
    __hip_bfloat16* sb = (t<8)? sA0 : sA1;
    *(bfrag*)(sb + 49*72 + (t&7)*8) = z;
  }

  int r0a[9], r1a[9];
  {
    int p0 = wm*32 + ln, p1 = p0+16;
    int y0=p0/7, x0=p0-y0*7, y1=p1/7, x1=p1-y1*7;
    bool v0=p0<49, v1=p1<49;
    #pragma unroll
    for (int koff=0;koff<9;koff++){
      int dy=koff/3-1, dx=koff-(koff/3)*3-1;
      int sy0=y0+dy,sx0=x0+dx, sy1=y1+dy,sx1=x1+dx;
      r0a[koff] = (v0&&sy0>=0&&sy0<7&&sx0>=0&&sx0<7)? sy0*7+sx0 : 49;
      r1a[koff] = (v1&&sy1>=0&&sy1<7&&sx1>=0&&sx1<7)? sy1*7+sx1 : 49;
    }
  }

  f32x4 acc2[2];
  acc2[0] = (f32x4){0.f,0.f,0.f,0.f};
  acc2[1] = (f32x4){0.f,0.f,0.f,0.f};

  const int i0r = t>>3, is8 = (t&7)*8;
  const int i1r = i0r + 32;
  const bool has1 = (t < 136);
  const __hip_bfloat16* Ab = A + (size_t)b*64*CC;

  *(bfrag*)(sA0 + i0r*72 + is8) = *(const bfrag*)(Ab + (size_t)i0r*CC + is8);
  if (has1)
    *(bfrag*)(sA0 + i1r*72 + is8) = *(const bfrag*)(Ab + (size_t)i1r*CC + is8);
  __syncthreads();

  const int nidx = nbb + wn*16 + ln;
  const __hip_bfloat16* wbase = Wb + (size_t)nidx*32 + quad*8;
  for (int c=0; c<9; c++){
    __hip_bfloat16* curb = (c&1)? sA1 : sA0;
    bfrag rs0, rs1;
    const bool pf = (c<8);
    if (pf){
      rs0 = *(const bfrag*)(Ab + (size_t)i0r*CC + (c+1)*64 + is8);
      if (has1) rs1 = *(const bfrag*)(Ab + (size_t)i1r*CC + (c+1)*64 + is8);
    }
    #pragma unroll
    for (int koff=0;koff<9;koff++){
      const int ra0 = r0a[koff]*72 + quad*8;
      const int ra1 = r1a[koff]*72 + quad*8;
      #pragma unroll
      for (int ks=0; ks<2; ks++){
        const __hip_bfloat16* wp = wbase + (size_t)(koff*18 + c*2 + ks)*18432;
        bfrag b0 = *(const bfrag*)(wp);
        bfrag a0 = *(const bfrag*)(curb + ra0 + ks*32);
        bfrag a1 = *(const bfrag*)(curb + ra1 + ks*32);
        acc2[0] = __builtin_amdgcn_mfma_f32_16x16x32_bf16(a0, b0, acc2[0], 0,0,0);
        acc2[1] = __builtin_amdgcn_mfma_f32_16x16x32_bf16(a1, b0, acc2[1], 0,0,0);
      }
    }
    if (pf){
      __hip_bfloat16* nxtb = (c&1)? sA0 : sA1;
      *(bfrag*)(nxtb + i0r*72 + is8) = rs0;
      if (has1) *(bfrag*)(nxtb + i1r*72 + is8) = rs1;
    }
    __syncthreads();
  }

  // epilogue: 32 ch x 49 px, 2 GN groups of 16 ch
  {
    const int chl = wn*16 + ln;
    float bv = ldin(bias, (size_t)bias_off + nbb + chl, isbf);
    #pragma unroll
    for (int mf=0; mf<2; mf++)
      #pragma unroll
      for (int r=0;r<4;r++){
        int px = wm*32 + mf*16 + quad*4 + r;
        s_out[chl*65 + px] = acc2[mf][r] + bv;
      }
  }
  __syncthreads();
  {
    int wv = t >> 6, l2 = t & 63;
    if (wv < 2){
      float s=0.f, ss=0.f;
      for (int j=l2; j<784; j+=64){
        int cq = j/49, px = j - cq*49;
        float v = s_out[(wv*16+cq)*65 + px];
        s += v; ss += v*v;
      }
      #pragma unroll
      for (int o=32;o>0;o>>=1){ s+=__shfl_down(s,o); ss+=__shfl_down(ss,o); }
      if (l2==0){
        float mean=s/784.f, var=ss/784.f-mean*mean;
        s_stats[wv*2]=mean; s_stats[wv*2+1]=rsqrtf(fmaxf(var,0.f)+1e-5f);
      }
    }
  }
  __syncthreads();
  if (t < 196){
    int px = t>>2, ck = t&3;
    alignas(16) __hip_bfloat16 tmp[8];
    #pragma unroll
    for (int u=0;u<8;u++){
      int chl = ck*8+u;
      int gi = chl>>4;
      float ga = ldin(gamma, (size_t)goff + nbb + chl, isbf);
      float be = ldin(beta,  (size_t)goff + nbb + chl, isbf);
      float v = (s_out[chl*65+px]-s_stats[gi*2])*s_stats[gi*2+1]*ga + be;
      tmp[u] = f2bf(fmaxf(v,0.f));
    }
    *(bfrag*)(out + ((size_t)b*64+px)*CC + nbb + ck*8) = *(const bfrag*)tmp;
  }
}

// ---- conv0 3x3 s2 p1 + GN + ReLU, chunked LDS A, MFMA (validated) --------
__global__ __launch_bounds__(256) void conv0_fused_kernel(
    const __hip_bfloat16* __restrict__ A,     // NHWC [64][196][256]
    const __hip_bfloat16* __restrict__ Wb,    // [9][8][576][32]
    const void* __restrict__ bias,
    const void* __restrict__ gamma, const void* __restrict__ beta,
    const int* __restrict__ flagp,
    __hip_bfloat16* __restrict__ out) {       // NHWC [64][64][576]
  const int t = threadIdx.x;
  const int l = t & 63, w = t >> 6;
  const int wm = w & 1, wn = w >> 1;
  const int ln = l & 15, quad = l >> 4;
  const int b = blockIdx.x, nbb = blockIdx.y*64;

  __shared__ alignas(16) __hip_bfloat16 sC[197*40];
  __shared__ alignas(16) float s_out_arr[64*65];
  __shared__ float s_stats[8];

  if (t < 4){
    bfrag z = {0,0,0,0,0,0,0,0};
    *(bfrag*)(sC + 196*40 + t*8) = z;
  }

  int yy[2], xx[2]; bool pv[2];
  #pragma unroll
  for (int mf=0; mf<2; mf++){
    int p = wm*32 + mf*16 + ln;
    pv[mf] = p<49; yy[mf]=p/7; xx[mf]=p-yy[mf]*7;
  }

  f32x4 acc[2][2];
  #pragma unroll
  for (int i=0;i<2;i++)
    #pragma unroll
    for (int j=0;j<2;j++) acc[i][j] = (f32x4){0.f,0.f,0.f,0.f};

  for (int icb=0; icb<8; icb++){
    __syncthreads();
    for (int idx=t*8; idx<6272; idx+=2048){
      int px = idx>>5, ic = idx&31;
      *(bfrag*)(sC + px*40 + ic) = *(const bfrag*)(A + ((size_t)b*196+px)*256 + icb*32 + ic);
    }
    __syncthreads();
    for (int koff=0; koff<9; koff++){
      const int dy = koff/3 - 1, dx = koff - (koff/3)*3 - 1;
      int sy0=2*yy[0]+dy, sx0=2*xx[0]+dx;
      int r0 = (pv[0]&&sy0>=0&&sy0<14&&sx0>=0&&sx0<14) ? sy0*14+sx0 : 196;
      int sy1=2*yy[1]+dy, sx1=2*xx[1]+dx;
      int r1 = (pv[1]&&sy1>=0&&sy1<14&&sx1>=0&&sx1<14) ? sy1*14+sx1 : 196;
      bfrag a0 = *(const bfrag*)(sC + r0*40 + quad*8);
      bfrag a1 = *(const bfrag*)(sC + r1*40 + quad*8);
      const __hip_bfloat16* wp = Wb + ((size_t)(koff*8+icb)*576 + nbb + wn*32 + ln)*32 + quad*8;
      bfrag b0 = *(const bfrag*)(wp);
      bfrag b1 = *(const bfrag*)(wp + 16*32);
      acc[0][0] = __builtin_amdgcn_mfma_f32_16x16x32_bf16(a0, b0, acc[0][0], 0,0,0);
      acc[1][0] = __builtin_amdgcn_mfma_f32_16x16x32_bf16(a1, b0, acc[1][0], 0,0,0);
      acc[0][1] = __builtin_amdgcn_mfma_f32_16x16x32_bf16(a0, b1, acc[0][1], 0,0,0);
      acc[1][1] = __builtin_amdgcn_mfma_f32_16x16x32_bf16(a1, b1, acc[1][1], 0,0,0);
    }
  }

  epilogue_gn(s_out_arr, s_stats, acc, wm, wn, ln, quad, t,
              bias, 0, gamma, beta, 0, nbb, *flagp, b, out);
}

// ---- depthwise 5x5 per edge: F NHWC -> Y[e][(b*49+px)][64] bf16 ----------
__global__ __launch_bounds__(256) void dw_edge_kernel(
    const __hip_bfloat16* __restrict__ F,
    const void* __restrict__ dw_w,   // [24][64][25]
    const void* __restrict__ dw_b,   // [24][64]
    const int* __restrict__ flagp,
    __hip_bfloat16* __restrict__ Y) {
  const int b = blockIdx.x, e = blockIdx.y, t = threadIdx.x;
  const int isbf = *flagp;
  const int src = EDGE_SRC_C[e];
  __shared__ alignas(16) __hip_bfloat16 sA[50*72];   // 49 px rows + zero row
  for (int idx=t; idx<400; idx+=256){
    if (idx < 392){
      int px = idx>>3, ic = (idx&7)*8;
      *(bfrag*)(sA + px*72 + ic) = *(const bfrag*)(F + ((size_t)b*64+px)*CC + src*64 + ic);
    } else {
      bfrag z = {0,0,0,0,0,0,0,0};
      *(bfrag*)(sA + 49*72 + (idx-392)*8) = z;
    }
  }
  __syncthreads();
  const int ch = t & 63, wv = t >> 6;
  float wd[25];
  #pragma unroll
  for (int j=0;j<25;j++) wd[j] = ldin(dw_w, (size_t)e*1600 + ch*25 + j, isbf);
  float dwb = ldin(dw_b, e*64 + ch, isbf);
  for (int px=wv; px<49; px+=4){
    int oy=px/7, ox=px-oy*7;
    float a = dwb;
    #pragma unroll
    for (int u=0;u<5;u++){
      int py = oy+u-2;
      bool vy = (py>=0)&&(py<7);
      #pragma unroll
      for (int v=0;v<5;v++){
        int pxx = ox+v-2;
        int r = (vy && pxx>=0 && pxx<7) ? py*7+pxx : 49;
        a += bf2f(sA[r*72 + ch]) * wd[u*5+v];
      }
    }
    Y[((size_t)(e*64+b)*49 + px)*64 + ch] = f2bf(a);
  }
}

// ---- pack pointwise weights to bf16 [24][64oc][64ic] ---------------------
__global__ __launch_bounds__(256) void pwpack_kernel(
    const void* __restrict__ pw_fo, const void* __restrict__ pw_so,
    const int* __restrict__ flagp,
    __hip_bfloat16* __restrict__ dfo, __hip_bfloat16* __restrict__ dso) {
  const int e = blockIdx.x, t = threadIdx.x;
  const int isbf = *flagp;
  for (int idx=t; idx<4096; idx+=256){
    dfo[(size_t)e*4096+idx] = f2bf(ldin(pw_fo, (size_t)e*4096+idx, isbf));
    dso[(size_t)e*4096+idx] = f2bf(ldin(pw_so, (size_t)e*4096+idx, isbf));
  }
}

// ---- pointwise + segment-sum via MFMA: out = base + sum_e Y_e @ pw_e^T ---
__global__ __launch_bounds__(256) void pw_seg_kernel(
    const __hip_bfloat16* __restrict__ Y,     // [24][3136][64]
    const __hip_bfloat16* __restrict__ base,  // NHWC [64][64][576]
    const __hip_bfloat16* __restrict__ pwb,   // [24][64oc][64ic] bf16
    const void* __restrict__ pw_b,            // [24][64] ext
    const int* __restrict__ flagp,
    __hip_bfloat16* __restrict__ out) {       // NHWC
  const int t = threadIdx.x, l = t & 63, w = t >> 6;
  const int wm = w & 1, wn = w >> 1;
  const int ln = l & 15, quad = l >> 4;
  const int dst = blockIdx.y;
  const int mt = blockIdx.x*64 + wm*32;
  const int m0 = mt + ln, m1 = m0 + 16;

  f32x4 acc[2][2];
  #pragma unroll
  for (int i=0;i<2;i++)
    #pragma unroll
    for (int j=0;j<2;j++) acc[i][j] = (f32x4){0.f,0.f,0.f,0.f};

  const int eoff = EDGE_OFF_C[dst], ecnt = EDGE_CNT_C[dst];
  for (int k=0;k<ecnt;k++){
    const __hip_bfloat16* Ye = Y + (size_t)(eoff+k)*3136*64;
    const __hip_bfloat16* pe = pwb + (size_t)(eoff+k)*4096;
    #pragma unroll
    for (int ks=0; ks<2; ks++){
      const int kq = ks*32 + quad*8;
      bfrag a0 = *(const bfrag*)(Ye + (size_t)m0*64 + kq);
      bfrag a1 = *(const bfrag*)(Ye + (size_t)m1*64 + kq);
      bfrag b0 = *(const bfrag*)(pe + (wn*32+ln)*64 + kq);
      bfrag b1 = *(const bfrag*)(pe + (wn*32+ln+16)*64 + kq);
      acc[0][0] = __builtin_amdgcn_mfma_f32_16x16x32_bf16(a0, b0, acc[0][0], 0,0,0);
      acc[1][0] = __builtin_amdgcn_mfma_f32_16x16x32_bf16(a1, b0, acc[1][0], 0,0,0);
      acc[0][1] = __builtin_amdgcn_mfma_f32_16x16x32_bf16(a0, b1, acc[0][1], 0,0,0);
      acc[1][1] = __builtin_amdgcn_mfma_f32_16x16x32_bf16(a1, b1, acc[1][1], 0,0,0);
    }
  }

  const int isbf = *flagp;
  #pragma unroll
  for (int nf=0; nf<2; nf++){
    int n = wn*32 + nf*16 + ln;
    float pbs = 0.f;
    for (int k=0;k<ecnt;k++) pbs += ldin(pw_b, (size_t)(eoff+k)*64 + n, isbf);
    #pragma unroll
    for (int mf=0; mf<2; mf++){
      #pragma unroll
      for (int r=0; r<4; r++){
        int m = mt + mf*16 + quad*4 + r;
        int bb = m/49, px = m - bb*49;
        size_t oi = ((size_t)bb*64 + px)*CC + dst*64 + n;
        out[oi] = f2bf(bf2f(base[oi]) + acc[mf][nf][r] + pbs);
      }
    }
  }
}

// ---- up1_w [576][64][16] ext -> wpack [9][16tap][64oc][64ic] bf16 --------
__global__ __launch_bounds__(256) void wpack_dc1_kernel(
    const void* __restrict__ w1, const int* __restrict__ flagp,
    __hip_bfloat16* __restrict__ dst) {
  const int gtap = blockIdx.x, t = threadIdx.x;
  const int isbf = *flagp;
  const int g = gtap >> 4, tap = gtap & 15;
  for (int idx=t; idx<64*64; idx+=256){
    int oc = idx >> 6, ic = idx & 63;
    dst[((size_t)gtap*64 + oc)*64 + ic] =
        f2bf(ldin(w1, ((size_t)(g*64+ic)*64 + oc)*16 + tap, isbf));
  }
}

// ---- deconv1 via parity-class MFMA: H NHWC -> mid NHWC [64][196][576] ----
// ConvTranspose2d(k=4,s=2,p=1): output pixel (oy,ox) uses exactly 2x2 taps
// with ky parity == (oy+1)&1, kx parity == (ox+1)&1. Grid (49 Mtiles, 4
// classes, 9 groups); M = 64b*49px per class tiles exactly into 49x64.
// NOTE: 64 consecutive m = b*49+p rows span up to THREE batches; three
// batch slices staged (slice 2 zero-filled when b0+2 > 63). Pad-72 stride.
__global__ __launch_bounds__(256) void dc1_cls_kernel(
    const __hip_bfloat16* __restrict__ H,    // NHWC [64][64(px pad)][576]
    const __hip_bfloat16* __restrict__ Wp,   // [(g*16+tap)][oc][ic]
    const void* __restrict__ b1,
    const int* __restrict__ flagp,
    __hip_bfloat16* __restrict__ mid) {
  const int t = threadIdx.x;
  const int l = t & 63, w = t >> 6;
  const int wm = w & 1, wn = w >> 1;
  const int ln = l & 15, quad = l >> 4;
  const int Mt = blockIdx.x;        // 0..48, 64 rows of (b*49+p)
  const int cls = blockIdx.y;       // ry*2+rx
  const int g = blockIdx.z;
  const int ry = cls >> 1, rx = cls & 1;
  const int b0 = (Mt*64)/49;        // block spans b0 .. b0+2 (guarded)

  __shared__ alignas(16) __hip_bfloat16 sX[3*50*72];  // [bloc][px(+zero)][ic]

  {
    const bfrag z = {0,0,0,0,0,0,0,0};
    for (int idx=t; idx<1200; idx+=256){
      int bi = idx/400, rem = idx - bi*400;
      int p = rem>>3, ch = (rem&7)*8;
      bfrag v = z;
      if (p < 49 && (b0+bi) < 64)
        v = *(const bfrag*)(H + ((size_t)((b0+bi)*64) + p)*CC + g*64 + ch);
      *(bfrag*)(sX + (bi*50+p)*72 + ch) = v;
    }
  }

  // per-lane A row offsets for the 4 taps of this class
  int aoff[2][4];
  #pragma unroll
  for (int mf=0; mf<2; mf++){
    int m = Mt*64 + wm*32 + mf*16 + ln;
    int b = m/49, p = m - b*49;
    int py = p/7, pxx = p - py*7;
    int bloc = b - b0;
    #pragma unroll
    for (int kyi=0;kyi<2;kyi++){
      int iy = py + ry - kyi;
      bool vy = (iy>=0)&&(iy<7);
      #pragma unroll
      for (int kxi=0;kxi<2;kxi++){
        int ix = pxx + rx - kxi;
        int r = (vy && ix>=0 && ix<7) ? iy*7+ix : 49;
        aoff[mf][kyi*2+kxi] = (bloc*50 + r)*72 + quad*8;
      }
    }
  }

  f32x4 acc[2][2];
  #pragma unroll
  for (int i=0;i<2;i++)
    #pragma unroll
    for (int j=0;j<2;j++) acc[i][j] = (f32x4){0.f,0.f,0.f,0.f};

  __syncthreads();

  const int ky0 = 1-ry, kx0 = 1-rx;
  #pragma unroll
  for (int kyi=0;kyi<2;kyi++){
    #pragma unroll
    for (int kxi=0;kxi<2;kxi++){
      const int tap = (ky0+2*kyi)*4 + (kx0+2*kxi);
      const __hip_bfloat16* wb =
          Wp + ((size_t)(g*16+tap)*64 + wn*32 + ln)*64 + quad*8;
      const int ao0 = aoff[0][kyi*2+kxi], ao1 = aoff[1][kyi*2+kxi];
      #pragma unroll
      for (int half=0; half<2; half++){
        bfrag a0 = *(const bfrag*)(sX + ao0 + half*32);
        bfrag a1 = *(const bfrag*)(sX + ao1 + half*32);
        bfrag w0 = *(const bfrag*)(wb + half*32);
        bfrag w1 = *(const bfrag*)(wb + 16*64 + half*32);
        acc[0][0] = __builtin_amdgcn_mfma_f32_16x16x32_bf16(a0, w0, acc[0][0], 0,0,0);
        acc[1][0] = __builtin_amdgcn_mfma_f32_16x16x32_bf16(a1, w0, acc[1][0], 0,0,0);
        acc[0][1] = __builtin_amdgcn_mfma_f32_16x16x32_bf16(a0, w1, acc[0][1], 0,0,0);
        acc[1][1] = __builtin_amdgcn_mfma_f32_16x16x32_bf16(a1, w1, acc[1][1], 0,0,0);
      }
    }
  }

  const int isbf = *flagp;
  size_t ob[2][4];
  #pragma unroll
  for (int mf=0;mf<2;mf++){
    #pragma unroll
    for (int r=0;r<4;r++){
      int m = Mt*64 + wm*32 + mf*16 + quad*4 + r;
      int b = m/49, p = m - b*49;
      int py = p/7, pxx = p - py*7;
      int oy = 2*py + ry, ox = 2*pxx + rx;
      ob[mf][r] = ((size_t)b*196 + oy*14 + ox)*CC + g*64;
    }
  }
  #pragma unroll
  for (int nf=0;nf<2;nf++){
    int n = wn*32 + nf*16 + ln;
    float bv = ldin(b1, g*64 + n, isbf);
    #pragma unroll
    for (int mf=0;mf<2;mf++){
      #pragma unroll
      for (int r=0;r<4;r++)
        mid[ob[mf][r] + n] = f2bf(acc[mf][nf][r] + bv);
    }
  }
}

// ---- fused GN(9)+ReLU+deconv2: mid NHWC -> out 28x28, split in 2 halves --
// grid (b, g, z): z=0 -> out rows 0..13 (in rows 0..7), z=1 -> 14..27 (6..13)
// (validated best: merged single-block variant regressed in R12 — the
//  deconv compute phase needs the 2x block parallelism more than the
//  stats pass needs dedup.)
__global__ __launch_bounds__(256) void dc2gn_kernel(
    const __hip_bfloat16* __restrict__ mid,   // [64][196][576] (bias only)
    const void* __restrict__ gamma, const void* __restrict__ beta,
    const void* __restrict__ w2,
    const void* __restrict__ b2,
    const int* __restrict__ flagp,
    void* __restrict__ outp,
    size_t out_elem_off) {
  const int isbf = *flagp;
  const int b=blockIdx.x, g=blockIdx.y, z=blockIdx.z, t=threadIdx.x;
  const int c = t & 63;
  __shared__ __hip_bfloat16 s_mid[64*113];   // [c][8 rows x 14 cols + pad]
  __shared__ float s_w2[64][17];
  __shared__ float red[8]; __shared__ float stats[2];
  const __hip_bfloat16* mbase = mid + (size_t)b*196*CC + g*64;

  // group stats (redundant per z-half; streams 25 KB from L2)
  {
    float s=0.f, ss=0.f;
    for (int idx=t; idx<12544; idx+=256){
      int ipx = idx>>6;
      float v = bf2f(mbase[(size_t)ipx*CC + (idx&63)]);
      s+=v; ss+=v*v;
    }
    #pragma unroll
    for (int o=32;o>0;o>>=1){ s+=__shfl_down(s,o); ss+=__shfl_down(ss,o); }
    int wid=t>>6;
    if ((t&63)==0){ red[wid]=s; red[4+wid]=ss; }
  }
  for (int idx=t; idx<1024; idx+=256)
    s_w2[idx>>4][idx&15] = ldin(w2, (g*SPC + (idx>>4))*16 + (idx&15), isbf);
  __syncthreads();
  if (t==0){
    float S=red[0]+red[1]+red[2]+red[3];
    float SS=red[4]+red[5]+red[6]+red[7];
    float mean=S/12544.f, var=SS/12544.f-mean*mean;
    stats[0]=mean; stats[1]=rsqrtf(fmaxf(var,0.f)+1e-5f);
  }
  __syncthreads();
  const float mean=stats[0], inv=stats[1];
  const int rbase = z*6;                 // input rows rbase..rbase+7
  {
    float ga = ldin(gamma, g*SPC+c, isbf), be = ldin(beta, g*SPC+c, isbf);
    for (int idx=t; idx<7168; idx+=256){
      int pl = idx>>6;                   // c = idx&63 == t&63 (stride 256)
      int ipx = (rbase + pl/14)*14 + (pl%14);
      float v = (bf2f(mbase[(size_t)ipx*CC + c])-mean)*inv*ga + be;
      s_mid[c*113 + pl] = f2bf(fmaxf(v, 0.f));
    }
  }
  __syncthreads();
  float b2v = ldin(b2, g, isbf);
  for (int p=t; p<392; p+=256){
    int oyl = p/28, ox = p - oyl*28;
    int oy = z*14 + oyl;
    float a = b2v;
    for (int cc=0; cc<64; cc++){
      #pragma unroll
      for (int kyi=0;kyi<2;kyi++){
        int ky=((oy+1)&1)+2*kyi; int ny=oy+1-ky;
        if (ny>=0){
          int iy=ny>>1;
          if (iy<14){
            int li = iy - rbase;     // in [0,8) by construction
            #pragma unroll
            for (int kxi=0;kxi<2;kxi++){
              int kx=((ox+1)&1)+2*kxi; int nx=ox+1-kx;
              if (nx>=0){
                int ix=nx>>1;
                if (ix<14) a += bf2f(s_mid[cc*113 + li*14 + ix])*s_w2[cc][ky*4+kx];
              }
            }
          }
        }
      }
    }
    size_t oidx = out_elem_off + ((size_t)b*NGR+g)*HW28 + oy*28 + ox;
    if (isbf) ((__hip_bfloat16*)outp)[oidx] = f2bf(a);
    else      ((float*)outp)[oidx] = a;
  }
}

extern "C" void kernel_launch(void* const* d_in, const int* in_sizes, int n_in,
                              void* d_out, int out_size, void* d_ws, size_t ws_size,
                              hipStream_t stream) {
  const void* x        = d_in[0];
  const void* convs_w0 = d_in[1];
  const void* convs_b0 = d_in[2];
  const void* convs_w  = d_in[3];
  const void* convs_b  = d_in[4];
  const void* gn_gamma = d_in[5];
  const void* gn_beta  = d_in[6];
  const void* fo_dw_w  = d_in[7];
  const void* fo_dw_b  = d_in[8];
  const void* fo_pw_w  = d_in[9];
  const void* fo_pw_b  = d_in[10];
  const void* so_dw_w  = d_in[11];
  const void* so_dw_b  = d_in[12];
  const void* so_pw_w  = d_in[13];
  const void* so_pw_b  = d_in[14];
  const void* up1_w    = d_in[15];
  const void* up1_b    = d_in[16];
  const void* sbn_g    = d_in[17];
  const void* sbn_b    = d_in[18];
  const void* up2_w    = d_in[19];
  const void* up2_b    = d_in[20];
  (void)in_sizes; (void)n_in; (void)out_size;

  int* flag = (int*)d_ws;
  char* wsb = (char*)d_ws + 16;
  __hip_bfloat16* act0   = (__hip_bfloat16*)(wsb);
  __hip_bfloat16* wbuf   = (__hip_bfloat16*)(wsb + 6422528);
  __hip_bfloat16* actA   = (__hip_bfloat16*)(wsb + 12394496);
  __hip_bfloat16* actB   = (__hip_bfloat16*)(wsb + 17113088);
  __hip_bfloat16* bufF   = (__hip_bfloat16*)(wsb + 21831680);
  __hip_bfloat16* secN   = (__hip_bfloat16*)(wsb + 26550272);
  __hip_bfloat16* wpack  = (__hip_bfloat16*)(wsb + 31268864);
  __hip_bfloat16* pwbF   = (__hip_bfloat16*)(wsb + 32448512);
  __hip_bfloat16* pwbS   = (__hip_bfloat16*)(wsb + 32645120);
  __hip_bfloat16* Y      = (__hip_bfloat16*)(wsb);
  __hip_bfloat16* mid    = (__hip_bfloat16*)(wsb);

  // merged weight-conversion buffer (7 layers), beyond all live buffers
  const size_t WL_ELEMS = (size_t)9*18*576*32;        // elems per layer
  const size_t wall_off = 33u*1024u*1024u;            // byte offset into wsb
  const bool bigws = ws_size >= 16 + wall_off + 7*WL_ELEMS*sizeof(__hip_bfloat16);
  __hip_bfloat16* wall = (__hip_bfloat16*)(wsb + wall_off);

  detect_kernel<<<1, 1, 0, stream>>>((const unsigned short*)x, flag);

  if (bigws)
    wcvtAll2_kernel<<<dim3(288,7), 256, 0, stream>>>(convs_w, flag, wall);

  xcvt_kernel<<<dim3(BB,8,7), 256, 0, stream>>>(x, flag, act0);
  wcvt0_kernel<<<CC, 256, 0, stream>>>(convs_w0, flag, wbuf);
  conv0_fused_kernel<<<dim3(64,9), 256, 0, stream>>>(
      act0, wbuf, convs_b0, gn_gamma, gn_beta, flag, actA);

  __hip_bfloat16* cur = actA; __hip_bfloat16* nxt = actB;
  for (int i=0;i<7;i++){
    const __hip_bfloat16* wb_i;
    if (bigws){
      wb_i = wall + (size_t)i*WL_ELEMS;
    } else {
      wcvtL_kernel<<<CC, 256, 0, stream>>>(convs_w, i, flag, wbuf);
      wb_i = wbuf;
    }
    conv3_v8_kernel<<<1152, 256, 0, stream>>>(
        cur, wb_i, convs_b, i*CC, gn_gamma, gn_beta, (i+1)*CC, flag, nxt);
    __hip_bfloat16* tmp=cur; cur=nxt; nxt=tmp;
  }
  // cur == actB (h, NHWC)

  wpack_dc1_kernel<<<144, 256, 0, stream>>>(up1_w, flag, wpack);
  pwpack_kernel<<<24, 256, 0, stream>>>(fo_pw_w, so_pw_w, flag, pwbF, pwbS);

  // edge pass 1: first = h + seg(pw(dw(h)))
  dw_edge_kernel<<<dim3(BB,24), 256, 0, stream>>>(cur, fo_dw_w, fo_dw_b, flag, Y);
  pw_seg_kernel<<<dim3(49,NGR), 256, 0, stream>>>(Y, cur, pwbF, fo_pw_b, flag, bufF);
  // edge pass 2: second = h + seg(pw(dw(first)))
  dw_edge_kernel<<<dim3(BB,24), 256, 0, stream>>>(bufF, so_dw_w, so_dw_b, flag, Y);
  pw_seg_kernel<<<dim3(49,NGR), 256, 0, stream>>>(Y, cur, pwbS, so_pw_b, flag, secN);

  // head 1 (input h = cur, NHWC)
  dc1_cls_kernel<<<dim3(49,4,NGR), 256, 0, stream>>>(cur, wpack, up1_b, flag, mid);
  dc2gn_kernel<<<dim3(BB,NGR,2), 256, 0, stream>>>(mid, sbn_g, sbn_b, up2_w, up2_b, flag, d_out, 0);
  // head 2 (input secN, NHWC)
  dc1_cls_kernel<<<dim3(49,4,NGR), 256, 0, stream>>>(secN, wpack, up1_b, flag, mid);
  dc2gn_kernel<<<dim3(BB,NGR,2), 256, 0, stream>>>(mid, sbn_g, sbn_b, up2_w, up2_b, flag, d_out, (size_t)BB*NGR*HW28);
}